// Round 7
// baseline (684.133 us; speedup 1.0000x reference)
//
#include <hip/hip_runtime.h>
#include <math.h>

#define N_NODES 32768
#define E_EDGES 524288
#define HIDDEN  256
#define NPG     512
#define NGRAPH  64
#define NHEAD   8
#define CDIM    32

typedef unsigned short bf16;
typedef __attribute__((ext_vector_type(8))) short short8;
typedef __attribute__((ext_vector_type(4))) float f4;

#define AS1 __attribute__((address_space(1)))
#define AS3 __attribute__((address_space(3)))

// async global->LDS 16B per lane; LDS dest must be wave-uniform base + lane*16
__device__ __forceinline__ void cp16(const bf16* g, bf16* l) {
    __builtin_amdgcn_global_load_lds((AS1 const unsigned int*)(const void*)g,
                                     (AS3 unsigned int*)(void*)l, 16, 0, 0);
}

// ---------------- bf16 helpers (manual, RNE) ----------------
__device__ inline float bf2f(unsigned short u) {
    union { unsigned int i; float f; } v; v.i = ((unsigned int)u) << 16; return v.f;
}
__device__ inline unsigned short f2bf(float f) {
    union { float f; unsigned int i; } v; v.f = f;
    unsigned int x = v.i;
    return (unsigned short)((x + 0x7FFFu + ((x >> 16) & 1u)) >> 16);
}
__device__ inline float4 load4(const float* p) { return *(const float4*)p; }
__device__ inline float4 load4(const bf16* p) {
    ushort4 u = *(const ushort4*)p;
    return make_float4(bf2f(u.x), bf2f(u.y), bf2f(u.z), bf2f(u.w));
}
__device__ inline void store4(float* p, float4 v) { *(float4*)p = v; }
__device__ inline void store4(bf16* p, float4 v) {
    ushort4 u; u.x = f2bf(v.x); u.y = f2bf(v.y); u.z = f2bf(v.z); u.w = f2bf(v.w);
    *(ushort4*)p = u;
}

// ---------------- small utility kernels ----------------

__global__ void zero_kernel(float* deg, float* ea_sum, int* fill) {
    int i = blockIdx.x * blockDim.x + threadIdx.x;
    if (i < 2 * N_NODES) ea_sum[i] = 0.0f;
    if (i < N_NODES) { deg[i] = 0.0f; fill[i] = 0; }
}

__global__ void deg_kernel(const int* __restrict__ ei, const float* __restrict__ edge_attr,
                           float* deg, float* ea_sum) {
    int e = blockIdx.x * blockDim.x + threadIdx.x;
    if (e >= E_EDGES) return;
    int d = ei[E_EDGES + e];
    atomicAdd(&deg[d], 1.0f);
    atomicAdd(&ea_sum[2 * d + 0], edge_attr[2 * e + 0]);
    atomicAdd(&ea_sum[2 * d + 1], edge_attr[2 * e + 1]);
}

__global__ void eamean_kernel(const float* __restrict__ deg, float* ea_mean) {
    int i = blockIdx.x * blockDim.x + threadIdx.x;
    if (i >= N_NODES) return;
    float dm = fmaxf(deg[i], 1.0f);
    ea_mean[2 * i + 0] /= dm;
    ea_mean[2 * i + 1] /= dm;
}

__global__ __launch_bounds__(1024) void scan_kernel(const float* __restrict__ deg, int* row_ptr) {
    __shared__ int part[1024];
    int t = threadIdx.x;
    int base = t * 32;
    int loc[32];
    int s = 0;
    #pragma unroll
    for (int j = 0; j < 32; j++) {
        loc[j] = s;
        s += (int)deg[base + j] + 1;
    }
    int mysum = s;
    part[t] = s;
    __syncthreads();
    for (int off = 1; off < 1024; off <<= 1) {
        int v = 0;
        if (t >= off) v = part[t - off];
        __syncthreads();
        part[t] += v;
        __syncthreads();
    }
    int offset = part[t] - mysum;
    #pragma unroll
    for (int j = 0; j < 32; j++) row_ptr[base + j] = offset + loc[j];
    if (t == 1023) row_ptr[N_NODES] = part[1023];
}

__global__ void fill_kernel(const int* __restrict__ ei, const int* __restrict__ row_ptr,
                            int* fill, int* col) {
    int tid = blockIdx.x * blockDim.x + threadIdx.x;
    if (tid >= E_EDGES + N_NODES) return;
    int d;
    if (tid < E_EDGES) d = ei[E_EDGES + tid];
    else               d = tid - E_EDGES;
    int pos = row_ptr[d] + atomicAdd(&fill[d], 1);
    col[pos] = tid;
}

// ---------------- all conversions in one launch ----------------
__global__ void convall(const float* __restrict__ x,
                        const float* __restrict__ W_l, const float* __restrict__ W_r,
                        const float* __restrict__ W1, const float* __restrict__ W2,
                        const float* __restrict__ in_proj_w, const float* __restrict__ out_proj_w,
                        const float* __restrict__ b_l, const float* __restrict__ b_r,
                        const float* __restrict__ in_proj_b,
                        bf16* xb, bf16* wcat, bf16* w1b, bf16* w2b,
                        bf16* wopb, float* bcat)
{
    int b = blockIdx.x, t = threadIdx.x;
    if (b < 8192) {                        // x copy
        int i = b * 256 + t;
        store4(&xb[i * 4], *(const float4*)&x[i * 4]);
    } else if (b < 8960) {                 // in_proj_w [768][256] straight -> wcat rows 0..767
        int i = (b - 8192) * 256 + t;
        wcat[i] = f2bf(in_proj_w[i]);
    } else if (b < 9216) {                 // W_l^T -> wcat rows 768..1023
        int i = (b - 8960) * 256 + t; int k = i >> 8, n = i & 255;
        wcat[(768 + n) * 256 + k] = f2bf(W_l[i]);
    } else if (b < 9472) {                 // W_r^T -> wcat rows 1024..1279
        int i = (b - 9216) * 256 + t; int k = i >> 8, n = i & 255;
        wcat[(1024 + n) * 256 + k] = f2bf(W_r[i]);
    } else if (b < 10496) {                // W1 [256][1024] -> w1b[n*256+k]
        int i = (b - 9472) * 256 + t; int k = i >> 10, n = i & 1023;
        w1b[n * 256 + k] = f2bf(W1[i]);
    } else if (b < 11520) {                // W2 [1024][256] -> w2b[n*1024+k]
        int i = (b - 10496) * 256 + t; int k = i >> 8, n = i & 255;
        w2b[n * 1024 + k] = f2bf(W2[i]);
    } else if (b < 11584) {                // out_proj_w straight
        int i = (b - 11520) * 256 + t;
        store4(&wopb[i * 4], *(const float4*)&out_proj_w[i * 4]);
    } else {                               // bcat: in_proj_b | b_l | b_r
        #pragma unroll
        for (int j = 0; j < 5; j++) {
            int idx = j * 256 + t;
            bcat[idx] = (idx < 768) ? in_proj_b[idx]
                      : (idx < 1024) ? b_l[idx - 768] : b_r[idx - 1024];
        }
    }
}

// ---------------- MFMA bf16 GEMM 128x128 (m97-style staging) ----------------
// EPI: 1 bias+gelu -> C ; 3 slab-split (256-col slabs -> C,res,d2)
template <int EPI>
__global__ __launch_bounds__(256) void mfma_gemm(
    const bf16* __restrict__ A, const bf16* __restrict__ Wb,
    const float* __restrict__ bias, const bf16* __restrict__ res,
    bf16* __restrict__ C, int M, int N, int K, bf16* __restrict__ d2)
{
    __shared__ bf16 lds[2 * 128 * 64];
    bf16* As = lds;
    bf16* Bs = lds + 128 * 64;
    int tid = threadIdx.x;
    int wave = tid >> 6, lane = tid & 63;
    int quad = lane >> 4, l16 = lane & 15;
    int n0 = blockIdx.x * 128, m0 = blockIdx.y * 128;
    int wm = (wave & 1) * 64, wn = (wave >> 1) * 64;

    f4 acc[4][4] = {};
    int srow = tid >> 3;
    int scol = (tid & 7) * 8;

    for (int k0 = 0; k0 < K; k0 += 64) {
        #pragma unroll
        for (int i = 0; i < 4; i++) {
            int row = i * 32 + srow;
            cp16(&A[(size_t)(m0 + row) * K + k0 + scol], &As[row * 64 + scol]);
            cp16(&Wb[(size_t)(n0 + row) * K + k0 + scol], &Bs[row * 64 + scol]);
        }
        __syncthreads();
        #pragma unroll
        for (int ks = 0; ks < 2; ks++) {
            short8 af[4], bfr[4];
            #pragma unroll
            for (int mt = 0; mt < 4; mt++)
                af[mt] = *(const short8*)&As[(wm + mt * 16 + l16) * 64 + ks * 32 + quad * 8];
            #pragma unroll
            for (int nt = 0; nt < 4; nt++)
                bfr[nt] = *(const short8*)&Bs[(wn + nt * 16 + l16) * 64 + ks * 32 + quad * 8];
            #pragma unroll
            for (int mt = 0; mt < 4; mt++)
                #pragma unroll
                for (int nt = 0; nt < 4; nt++)
                    acc[mt][nt] = __builtin_amdgcn_mfma_f32_16x16x32_bf16(
                        af[mt], bfr[nt], acc[mt][nt], 0, 0, 0);
        }
        __syncthreads();
    }

    // epilogue: per-wave LDS transpose for coalesced bf16 stores
    float* epi = (float*)lds + wave * 16 * 68;
    int row = lane >> 2;
    int cb = (lane & 3) * 16;
    int gn = n0 + wn + cb;
    float bb[16];
    *(float4*)&bb[0]  = *(const float4*)&bias[gn + 0];
    *(float4*)&bb[4]  = *(const float4*)&bias[gn + 4];
    *(float4*)&bb[8]  = *(const float4*)&bias[gn + 8];
    *(float4*)&bb[12] = *(const float4*)&bias[gn + 12];

    for (int mt = 0; mt < 4; mt++) {
        #pragma unroll
        for (int nt = 0; nt < 4; nt++)
            #pragma unroll
            for (int r = 0; r < 4; r++)
                epi[(quad * 4 + r) * 68 + nt * 16 + l16] = acc[mt][nt][r];
        float vv[16];
        *(float4*)&vv[0]  = *(float4*)&epi[row * 68 + cb + 0];
        *(float4*)&vv[4]  = *(float4*)&epi[row * 68 + cb + 4];
        *(float4*)&vv[8]  = *(float4*)&epi[row * 68 + cb + 8];
        *(float4*)&vv[12] = *(float4*)&epi[row * 68 + cb + 12];
        int gm = m0 + wm + mt * 16 + row;
        #pragma unroll
        for (int j = 0; j < 16; j++) vv[j] += bb[j];
        if (EPI == 1) {
            #pragma unroll
            for (int j = 0; j < 16; j++)
                vv[j] = 0.5f * vv[j] * (1.0f + erff(vv[j] * 0.70710678118654752f));
        }
        ushort o16[16];
        #pragma unroll
        for (int j = 0; j < 16; j++) o16[j] = f2bf(vv[j]);
        bf16* cp;
        if (EPI == 3) {
            int slab = gn >> 8;
            bf16* dst = (slab == 0) ? C : (slab == 1) ? (bf16*)res : d2;
            cp = &dst[(size_t)gm * 256 + (gn & 255)];
        } else {
            cp = &C[(size_t)gm * N + gn];
        }
        *(int4*)&cp[0] = *(int4*)&o16[0];
        *(int4*)&cp[8] = *(int4*)&o16[8];
    }
}

// ---------------- 64x256 GEMM + fused row-LN epilogue ----------------
// FINAL=0: out_proj -> LN2 -> combined = a*local + (1-a)*n   (bf16 out)
// FINAL=1: ffn2 -> +residual(aux) -> LN3 -> fp32 out
template <int FINAL>
__global__ __launch_bounds__(256) void gemm_ln(
    const bf16* __restrict__ A, const bf16* __restrict__ Wb,
    const float* __restrict__ bias, const bf16* __restrict__ aux,
    const float* __restrict__ alpha_p,
    const float* __restrict__ gamma, const float* __restrict__ beta,
    void* Cout, int M, int K)
{
    __shared__ bf16 As[64 * 64];
    __shared__ bf16 Bs[256 * 64];
    __shared__ float rsum[4][64];
    __shared__ float rsq[4][64];
    int tid = threadIdx.x;
    int wave = tid >> 6, lane = tid & 63;
    int quad = lane >> 4, l16 = lane & 15;
    int m0 = blockIdx.x * 64;
    int wn = wave * 64;
    f4 acc[4][4] = {};
    int srow = tid >> 3, scol = (tid & 7) * 8;

    for (int k0 = 0; k0 < K; k0 += 64) {
        #pragma unroll
        for (int i = 0; i < 10; i++) {
            int vr = i * 32 + srow;
            if (vr < 64)
                cp16(&A[(size_t)(m0 + vr) * K + k0 + scol], &As[vr * 64 + scol]);
            else
                cp16(&Wb[(size_t)(vr - 64) * K + k0 + scol], &Bs[(vr - 64) * 64 + scol]);
        }
        __syncthreads();
        #pragma unroll
        for (int ks = 0; ks < 2; ks++) {
            short8 af[4], bfr[4];
            #pragma unroll
            for (int mt = 0; mt < 4; mt++)
                af[mt] = *(const short8*)&As[(mt * 16 + l16) * 64 + ks * 32 + quad * 8];
            #pragma unroll
            for (int nt = 0; nt < 4; nt++)
                bfr[nt] = *(const short8*)&Bs[(wn + nt * 16 + l16) * 64 + ks * 32 + quad * 8];
            #pragma unroll
            for (int mt = 0; mt < 4; mt++)
                #pragma unroll
                for (int nt = 0; nt < 4; nt++)
                    acc[mt][nt] = __builtin_amdgcn_mfma_f32_16x16x32_bf16(
                        af[mt], bfr[nt], acc[mt][nt], 0, 0, 0);
        }
        __syncthreads();
    }

    // bias (+ residual for FINAL)
    float bb[4];
    #pragma unroll
    for (int nt = 0; nt < 4; nt++) bb[nt] = bias[wn + nt * 16 + l16];
    #pragma unroll
    for (int mt = 0; mt < 4; mt++)
        #pragma unroll
        for (int nt = 0; nt < 4; nt++)
            #pragma unroll
            for (int r = 0; r < 4; r++) {
                acc[mt][nt][r] += bb[nt];
                if (FINAL) {
                    int row = mt * 16 + quad * 4 + r;
                    int col = wn + nt * 16 + l16;
                    acc[mt][nt][r] += bf2f(aux[(size_t)(m0 + row) * 256 + col]);
                }
            }

    // row stats: intra-wave over 64 cols, then cross-wave via LDS
    #pragma unroll
    for (int mt = 0; mt < 4; mt++)
        #pragma unroll
        for (int r = 0; r < 4; r++) {
            float s = 0.f, qq = 0.f;
            #pragma unroll
            for (int nt = 0; nt < 4; nt++) {
                float v = acc[mt][nt][r];
                s += v; qq += v * v;
            }
            s += __shfl_xor(s, 1); qq += __shfl_xor(qq, 1);
            s += __shfl_xor(s, 2); qq += __shfl_xor(qq, 2);
            s += __shfl_xor(s, 4); qq += __shfl_xor(qq, 4);
            s += __shfl_xor(s, 8); qq += __shfl_xor(qq, 8);
            if (l16 == 0) {
                int row = mt * 16 + quad * 4 + r;
                rsum[wave][row] = s;
                rsq[wave][row] = qq;
            }
        }
    __syncthreads();

    float aco = 0.f;
    if (!FINAL) aco = 1.f / (1.f + __expf(-alpha_p[0]));
    float gg[4], bt[4];
    #pragma unroll
    for (int nt = 0; nt < 4; nt++) {
        gg[nt] = gamma[wn + nt * 16 + l16];
        bt[nt] = beta[wn + nt * 16 + l16];
    }

    #pragma unroll
    for (int mt = 0; mt < 4; mt++)
        #pragma unroll
        for (int r = 0; r < 4; r++) {
            int row = mt * 16 + quad * 4 + r;
            float tot  = rsum[0][row] + rsum[1][row] + rsum[2][row] + rsum[3][row];
            float totq = rsq[0][row] + rsq[1][row] + rsq[2][row] + rsq[3][row];
            float mean = tot * (1.0f / 256.0f);
            float var = totq * (1.0f / 256.0f) - mean * mean;
            float rstd = rsqrtf(var + 1e-5f);
            size_t gm = (size_t)(m0 + row);
            #pragma unroll
            for (int nt = 0; nt < 4; nt++) {
                int col = wn + nt * 16 + l16;
                float nv = (acc[mt][nt][r] - mean) * rstd * gg[nt] + bt[nt];
                if (FINAL) {
                    ((float*)Cout)[gm * 256 + col] = nv;
                } else {
                    float lv = bf2f(aux[gm * 256 + col]);
                    ((bf16*)Cout)[gm * 256 + col] = f2bf(aco * lv + (1.f - aco) * nv);
                }
            }
        }
}

// ---------------- MFMA flash attention (split q/k/v buffers) ----------
__global__ __launch_bounds__(256) void attn_mfma(
    const bf16* __restrict__ q, const bf16* __restrict__ k, const bf16* __restrict__ v,
    bf16* __restrict__ attnout)
{
    __shared__ bf16 Ks[128 * 40];        // [key][d] stride 40
    __shared__ bf16 Vt[32 * 136];        // [d][key] stride 136
    __shared__ bf16 Pb[4 * 64 * 40];     // per-wave [q][key(32)+pad]
    __shared__ float lsumS[4][64];

    int b = blockIdx.x;
    int g = b >> 4, h = (b >> 1) & 7, hlf = b & 1;
    int tid = threadIdx.x;
    int wave = tid >> 6, lane = tid & 63;
    int quad = lane >> 4, l16 = lane & 15;
    int qbase = hlf * 256 + wave * 64;
    bf16* Pw = &Pb[wave * 64 * 40];
    const float SCALE = 0.17677669529663687f;

    short8 qf[4];
    #pragma unroll
    for (int qt = 0; qt < 4; qt++) {
        size_t node = (size_t)(g * NPG + qbase + qt * 16 + l16);
        qf[qt] = *(const short8*)&q[node * 256 + h * CDIM + quad * 8];
    }

    f4 oacc[4][2] = {};
    float ls[4] = {0.f, 0.f, 0.f, 0.f};

    for (int c = 0; c < 4; c++) {
        int kk0 = c * 128;
        __syncthreads();
        #pragma unroll
        for (int i = 0; i < 2; i++) {
            int idx = i * 256 + tid;
            int key = idx >> 2, kc = (idx & 3) * 8;
            *(int4*)&Ks[key * 40 + kc] =
                *(const int4*)&k[(size_t)(g * NPG + kk0 + key) * 256 + h * CDIM + kc];
        }
        {
            int key = tid >> 1, dblk = (tid & 1) * 16;
            ushort tmp[16];
            const bf16* vp = &v[(size_t)(g * NPG + kk0 + key) * 256 + h * CDIM + dblk];
            *(int4*)&tmp[0] = *(const int4*)&vp[0];
            *(int4*)&tmp[8] = *(const int4*)&vp[8];
            #pragma unroll
            for (int j = 0; j < 16; j++) Vt[(dblk + j) * 136 + key] = tmp[j];
        }
        __syncthreads();

        for (int sub = 0; sub < 4; sub++) {
            int ks0 = sub * 32;
            short8 kf[2];
            #pragma unroll
            for (int kt = 0; kt < 2; kt++)
                kf[kt] = *(const short8*)&Ks[(ks0 + kt * 16 + l16) * 40 + quad * 8];
            #pragma unroll
            for (int kt = 0; kt < 2; kt++) {
                #pragma unroll
                for (int qt = 0; qt < 4; qt++) {
                    f4 z = {0.f, 0.f, 0.f, 0.f};
                    f4 st = __builtin_amdgcn_mfma_f32_16x16x32_bf16(kf[kt], qf[qt], z, 0, 0, 0);
                    ushort pk[4];
                    float s4 = 0.f;
                    #pragma unroll
                    for (int r = 0; r < 4; r++) {
                        float p = __expf(st[r] * SCALE);
                        s4 += p;
                        pk[r] = f2bf(p);
                    }
                    ls[qt] += s4;
                    *(uint2*)&Pw[(qt * 16 + l16) * 40 + kt * 16 + quad * 4] = *(uint2*)pk;
                }
            }
            short8 vf[2];
            #pragma unroll
            for (int dt = 0; dt < 2; dt++)
                vf[dt] = *(const short8*)&Vt[(dt * 16 + l16) * 136 + ks0 + quad * 8];
            #pragma unroll
            for (int mt = 0; mt < 4; mt++) {
                short8 pf = *(const short8*)&Pw[(mt * 16 + l16) * 40 + quad * 8];
                #pragma unroll
                for (int dt = 0; dt < 2; dt++)
                    oacc[mt][dt] = __builtin_amdgcn_mfma_f32_16x16x32_bf16(
                        pf, vf[dt], oacc[mt][dt], 0, 0, 0);
            }
        }
    }

    #pragma unroll
    for (int qt = 0; qt < 4; qt++) {
        float l = ls[qt];
        l += __shfl_xor(l, 16);
        l += __shfl_xor(l, 32);
        if (quad == 0) lsumS[wave][qt * 16 + l16] = l;
    }
    __builtin_amdgcn_s_waitcnt(0);

    #pragma unroll
    for (int mt = 0; mt < 4; mt++) {
        #pragma unroll
        for (int dt = 0; dt < 2; dt++) {
            #pragma unroll
            for (int r = 0; r < 4; r++) {
                float denom = lsumS[wave][mt * 16 + quad * 4 + r];
                float val = oacc[mt][dt][r] / denom;
                size_t node = (size_t)(g * NPG + qbase + mt * 16 + quad * 4 + r);
                attnout[node * 256 + h * CDIM + dt * 16 + l16] = f2bf(val);
            }
        }
    }
}

// ---------------- GATv2 v3 (proven 104.7us): 2 waves/node + pipeline + LN1 ----
__device__ __forceinline__ void fetchmeta(
    int i, int re, int node, const int* __restrict__ col, const int* __restrict__ ei,
    const float* __restrict__ edge_attr, const float* __restrict__ ea_mean,
    int& s, float& a0, float& a1)
{
    if (i < re) {
        int e = col[i];
        if (e < E_EDGES) {
            s = ei[e]; a0 = edge_attr[2 * e]; a1 = edge_attr[2 * e + 1];
        } else {
            s = node; a0 = ea_mean[2 * node]; a1 = ea_mean[2 * node + 1];
        }
    } else {
        s = node; a0 = 0.f; a1 = 0.f;
    }
}

__global__ __launch_bounds__(256) void gat_kernel(
    const bf16* __restrict__ xl, const bf16* __restrict__ xr,
    const int* __restrict__ row_ptr, const int* __restrict__ col,
    const int* __restrict__ ei, const float* __restrict__ edge_attr,
    const float* __restrict__ ea_mean,
    const float* __restrict__ W_e, const float* __restrict__ att,
    const float* __restrict__ bias_gat,
    const float* __restrict__ g1, const float* __restrict__ be1,
    bf16* __restrict__ out)
{
    __shared__ float pacc[2][260];
    __shared__ float plsum[2][64];
    int wave = threadIdx.x >> 6;
    int lane = threadIdx.x & 63;
    int nloc = wave >> 1, half = wave & 1;
    int node = blockIdx.x * 2 + nloc;
    int cb = lane * 4;

    float4 xr4 = load4(&xr[(size_t)node * 256 + cb]);
    float4 we0 = *(const float4*)&W_e[cb];
    float4 we1 = *(const float4*)&W_e[HIDDEN + cb];
    float4 at4 = *(const float4*)&att[cb];

    int rs = row_ptr[node], re = row_ptr[node + 1];

    float lsum = 0.f;
    float acc0 = 0.f, acc1 = 0.f, acc2 = 0.f, acc3 = 0.f;

    int i0 = rs + half;
    int s0, s1; float a00, a01, a10, a11;
    fetchmeta(i0,     re, node, col, ei, edge_attr, ea_mean, s0, a00, a01);
    fetchmeta(i0 + 2, re, node, col, ei, edge_attr, ea_mean, s1, a10, a11);
    ushort4 xu0 = *(const ushort4*)&xl[(size_t)s0 * 256 + cb];

    for (int i = i0; i < re; i += 2) {
        int s2; float a20, a21;
        fetchmeta(i + 4, re, node, col, ei, edge_attr, ea_mean, s2, a20, a21);
        ushort4 xu1 = *(const ushort4*)&xl[(size_t)s1 * 256 + cb];

        float4 xl4 = make_float4(bf2f(xu0.x), bf2f(xu0.y), bf2f(xu0.z), bf2f(xu0.w));
        float t, p = 0.f;
        t = xl4.x + xr4.x + a00 * we0.x + a01 * we1.x; t = (t > 0.f) ? t : 0.2f * t; p += t * at4.x;
        t = xl4.y + xr4.y + a00 * we0.y + a01 * we1.y; t = (t > 0.f) ? t : 0.2f * t; p += t * at4.y;
        t = xl4.z + xr4.z + a00 * we0.z + a01 * we1.z; t = (t > 0.f) ? t : 0.2f * t; p += t * at4.z;
        t = xl4.w + xr4.w + a00 * we0.w + a01 * we1.w; t = (t > 0.f) ? t : 0.2f * t; p += t * at4.w;
        p += __shfl_xor(p, 1);
        p += __shfl_xor(p, 2);
        p += __shfl_xor(p, 4);
        float w = __expf(p);
        lsum += w;
        acc0 += w * xl4.x; acc1 += w * xl4.y; acc2 += w * xl4.z; acc3 += w * xl4.w;

        s0 = s1; a00 = a10; a01 = a11; xu0 = xu1;
        s1 = s2; a10 = a20; a11 = a21;
    }

    if (half) {
        plsum[nloc][lane] = lsum;
        pacc[nloc][cb + 0] = acc0; pacc[nloc][cb + 1] = acc1;
        pacc[nloc][cb + 2] = acc2; pacc[nloc][cb + 3] = acc3;
    }
    __syncthreads();
    if (!half) {
        lsum += plsum[nloc][lane];
        acc0 += pacc[nloc][cb + 0]; acc1 += pacc[nloc][cb + 1];
        acc2 += pacc[nloc][cb + 2]; acc3 += pacc[nloc][cb + 3];

        float inv = 1.0f / lsum;
        float v0 = acc0 * inv + bias_gat[cb + 0];
        float v1 = acc1 * inv + bias_gat[cb + 1];
        float v2 = acc2 * inv + bias_gat[cb + 2];
        float v3 = acc3 * inv + bias_gat[cb + 3];

        float s = v0 + v1 + v2 + v3;
        #pragma unroll
        for (int m = 1; m < 64; m <<= 1) s += __shfl_xor(s, m);
        float mean = s * (1.0f / 256.0f);
        float d0 = v0 - mean, d1 = v1 - mean, d2 = v2 - mean, d3 = v3 - mean;
        float sq = d0 * d0 + d1 * d1 + d2 * d2 + d3 * d3;
        #pragma unroll
        for (int m = 1; m < 64; m <<= 1) sq += __shfl_xor(sq, m);
        float rstd = rsqrtf(sq * (1.0f / 256.0f) + 1e-5f);
        float4 o;
        o.x = d0 * rstd * g1[cb + 0] + be1[cb + 0];
        o.y = d1 * rstd * g1[cb + 1] + be1[cb + 1];
        o.z = d2 * rstd * g1[cb + 2] + be1[cb + 2];
        o.w = d3 * rstd * g1[cb + 3] + be1[cb + 3];
        store4(&out[(size_t)node * HIDDEN + cb], o);
    }
}

// ---------------- launch ----------------
extern "C" void kernel_launch(void* const* d_in, const int* in_sizes, int n_in,
                              void* d_out, int out_size, void* d_ws, size_t ws_size,
                              hipStream_t stream) {
    const float* x          = (const float*)d_in[0];
    const float* edge_attr  = (const float*)d_in[1];
    const float* W_l        = (const float*)d_in[2];
    const float* b_l        = (const float*)d_in[3];
    const float* W_r        = (const float*)d_in[4];
    const float* b_r        = (const float*)d_in[5];
    const float* W_e        = (const float*)d_in[6];
    const float* att        = (const float*)d_in[7];
    const float* bias_gat   = (const float*)d_in[8];
    const float* in_proj_w  = (const float*)d_in[9];
    const float* in_proj_b  = (const float*)d_in[10];
    const float* out_proj_w = (const float*)d_in[11];
    const float* out_proj_b = (const float*)d_in[12];
    const float* alpha_p    = (const float*)d_in[13];
    const float* W1         = (const float*)d_in[14];
    const float* b1         = (const float*)d_in[15];
    const float* W2         = (const float*)d_in[16];
    const float* b2         = (const float*)d_in[17];
    const float* g1  = (const float*)d_in[18];
    const float* be1 = (const float*)d_in[19];
    const float* g2  = (const float*)d_in[20];
    const float* be2 = (const float*)d_in[21];
    const float* g3  = (const float*)d_in[22];
    const float* be3 = (const float*)d_in[23];
    const int* edge_index = (const int*)d_in[24];

    char* base = (char*)d_ws;
    const size_t MB = 1024 * 1024;
    const size_t KB = 1024;
    // graph prep [0, 3 MiB)
    float* deg     = (float*)(base + 0);
    float* ea_mean = (float*)(base + 131072);
    int*   fill    = (int*)  (base + 393216);
    int*   row_ptr = (int*)  (base + 524288);
    int*   col     = (int*)  (base + 786432);
    // weights [3 MiB, 6 MiB)
    bf16* wcat = (bf16*)(base + 3 * MB);               // 1280x256 (640 KB)
    bf16* w1b  = (bf16*)(base + 3 * MB + 704 * KB);    // 1024x256 (512 KB)
    bf16* w2b  = (bf16*)(base + 3 * MB + 1216 * KB);   // 256x1024 (512 KB)
    bf16* wopb = (bf16*)(base + 3 * MB + 1728 * KB);   // 256x256  (128 KB)
    float* bcat = (float*)(base + 5 * MB);             // 1280 floats
    // big buffers (aliased; peak 86 MiB)
    bf16* xb       = (bf16*)(base + 6 * MB);    // [6,22)
    bf16* xl       = (bf16*)(base + 22 * MB);   // [22,38)
    bf16* xr       = (bf16*)(base + 38 * MB);   // [38,54)
    bf16* localout = (bf16*)(base + 54 * MB);   // [54,70)
    bf16* qb       = (bf16*)(base + 22 * MB);   // [22,38)  (xl dead after gat)
    bf16* kb       = (bf16*)(base + 38 * MB);   // [38,54)  (xr dead after gat)
    bf16* vb       = (bf16*)(base + 70 * MB);   // [70,86)
    bf16* attnout  = (bf16*)(base + 6 * MB);    // [6,22)   (xb dead after qkv gemm)
    bf16* combined = (bf16*)(base + 22 * MB);   // [22,38)  (qb dead after attn)
    bf16* h1h      = (bf16*)(base + 38 * MB);   // [38,70)  (kb/localout dead)
    float* out = (float*)d_out;

    // ---- GAT graph prep ----
    zero_kernel<<<(2 * N_NODES + 255) / 256, 256, 0, stream>>>(deg, ea_mean, fill);
    deg_kernel<<<E_EDGES / 256, 256, 0, stream>>>(edge_index, edge_attr, deg, ea_mean);
    eamean_kernel<<<N_NODES / 256, 256, 0, stream>>>(deg, ea_mean);
    scan_kernel<<<1, 1024, 0, stream>>>(deg, row_ptr);
    fill_kernel<<<(E_EDGES + N_NODES) / 256, 256, 0, stream>>>(edge_index, row_ptr, fill, col);

    // ---- conversions (single launch) ----
    convall<<<11585, 256, 0, stream>>>(x, W_l, W_r, W1, W2, in_proj_w, out_proj_w,
                                       b_l, b_r, in_proj_b, xb, wcat, w1b, w2b, wopb, bcat);

    // ---- GAT path: xl|xr split GEMM then gather ----
    mfma_gemm<3><<<dim3(4, 256), 256, 0, stream>>>(
        xb, wcat + 768 * 256, bcat + 768, xr, xl, N_NODES, 512, 256, (bf16*)nullptr);
    gat_kernel<<<N_NODES / 2, 256, 0, stream>>>(
        xl, xr, row_ptr, col, edge_index, edge_attr, ea_mean,
        W_e, att, bias_gat, g1, be1, localout);

    // ---- MHA path: q|k|v split GEMM, attention, fused out_proj+LN2+combine ----
    mfma_gemm<3><<<dim3(6, 256), 256, 0, stream>>>(
        xb, wcat, bcat, kb, qb, N_NODES, 768, 256, vb);
    attn_mfma<<<NGRAPH * NHEAD * 2, 256, 0, stream>>>(qb, kb, vb, attnout);
    gemm_ln<0><<<512, 256, 0, stream>>>(
        attnout, wopb, out_proj_b, localout, alpha_p, g2, be2,
        (void*)combined, N_NODES, 256);

    // ---- FFN in two M-halves; ffn2 fused with residual+LN3 -> fp32 out ----
    for (int hh = 0; hh < 2; hh++) {
        const bf16* ch = combined + (size_t)hh * 16384 * 256;
        float* oh = out + (size_t)hh * 16384 * 256;
        mfma_gemm<1><<<dim3(8, 128), 256, 0, stream>>>(
            ch, w1b, b1, (const bf16*)nullptr, h1h, 16384, 1024, 256, (bf16*)nullptr);
        gemm_ln<1><<<256, 256, 0, stream>>>(
            h1h, w2b, b2, ch, alpha_p, g3, be3, (void*)oh, 16384, 1024);
    }
}

// Round 8
// 590.713 us; speedup vs baseline: 1.1581x; 1.1581x over previous
//
#include <hip/hip_runtime.h>
#include <math.h>

#define N_NODES 32768
#define E_EDGES 524288
#define HIDDEN  256
#define NPG     512
#define NGRAPH  64
#define NHEAD   8
#define CDIM    32

typedef unsigned short bf16;
typedef __attribute__((ext_vector_type(8))) short short8;
typedef __attribute__((ext_vector_type(4))) float f4;

#define AS1 __attribute__((address_space(1)))
#define AS3 __attribute__((address_space(3)))

// async global->LDS 16B per lane; LDS dest must be wave-uniform base + lane*16
__device__ __forceinline__ void cp16(const bf16* g, bf16* l) {
    __builtin_amdgcn_global_load_lds((AS1 const unsigned int*)(const void*)g,
                                     (AS3 unsigned int*)(void*)l, 16, 0, 0);
}

// ---------------- bf16 helpers (manual, RNE) ----------------
__device__ inline float bf2f(unsigned short u) {
    union { unsigned int i; float f; } v; v.i = ((unsigned int)u) << 16; return v.f;
}
__device__ inline unsigned short f2bf(float f) {
    union { float f; unsigned int i; } v; v.f = f;
    unsigned int x = v.i;
    return (unsigned short)((x + 0x7FFFu + ((x >> 16) & 1u)) >> 16);
}
__device__ inline float4 load4(const float* p) { return *(const float4*)p; }
__device__ inline float4 load4(const bf16* p) {
    ushort4 u = *(const ushort4*)p;
    return make_float4(bf2f(u.x), bf2f(u.y), bf2f(u.z), bf2f(u.w));
}
__device__ inline void store4(float* p, float4 v) { *(float4*)p = v; }
__device__ inline void store4(bf16* p, float4 v) {
    ushort4 u; u.x = f2bf(v.x); u.y = f2bf(v.y); u.z = f2bf(v.z); u.w = f2bf(v.w);
    *(ushort4*)p = u;
}

// ---------------- small utility kernels ----------------

__global__ void zero_kernel(float* deg, float* ea_sum, int* fill) {
    int i = blockIdx.x * blockDim.x + threadIdx.x;
    if (i < 2 * N_NODES) ea_sum[i] = 0.0f;
    if (i < N_NODES) { deg[i] = 0.0f; fill[i] = 0; }
}

__global__ void deg_kernel(const int* __restrict__ ei, const float* __restrict__ edge_attr,
                           float* deg, float* ea_sum) {
    int e = blockIdx.x * blockDim.x + threadIdx.x;
    if (e >= E_EDGES) return;
    int d = ei[E_EDGES + e];
    atomicAdd(&deg[d], 1.0f);
    atomicAdd(&ea_sum[2 * d + 0], edge_attr[2 * e + 0]);
    atomicAdd(&ea_sum[2 * d + 1], edge_attr[2 * e + 1]);
}

__global__ void eamean_kernel(const float* __restrict__ deg, float* ea_mean) {
    int i = blockIdx.x * blockDim.x + threadIdx.x;
    if (i >= N_NODES) return;
    float dm = fmaxf(deg[i], 1.0f);
    ea_mean[2 * i + 0] /= dm;
    ea_mean[2 * i + 1] /= dm;
}

__global__ __launch_bounds__(1024) void scan_kernel(const float* __restrict__ deg, int* row_ptr) {
    __shared__ int part[1024];
    int t = threadIdx.x;
    int base = t * 32;
    int loc[32];
    int s = 0;
    #pragma unroll
    for (int j = 0; j < 32; j++) {
        loc[j] = s;
        s += (int)deg[base + j] + 1;
    }
    int mysum = s;
    part[t] = s;
    __syncthreads();
    for (int off = 1; off < 1024; off <<= 1) {
        int v = 0;
        if (t >= off) v = part[t - off];
        __syncthreads();
        part[t] += v;
        __syncthreads();
    }
    int offset = part[t] - mysum;
    #pragma unroll
    for (int j = 0; j < 32; j++) row_ptr[base + j] = offset + loc[j];
    if (t == 1023) row_ptr[N_NODES] = part[1023];
}

// CSR fill with PACKED 16B edge records: {src, ea0_bits, ea1_bits, 0}
__global__ void fill_kernel(const int* __restrict__ ei, const float* __restrict__ edge_attr,
                            const float* __restrict__ ea_mean,
                            const int* __restrict__ row_ptr, int* fill, int4* __restrict__ erec) {
    int tid = blockIdx.x * blockDim.x + threadIdx.x;
    if (tid >= E_EDGES + N_NODES) return;
    int d, src; float a0, a1;
    if (tid < E_EDGES) {
        d = ei[E_EDGES + tid];
        src = ei[tid];
        a0 = edge_attr[2 * tid + 0];
        a1 = edge_attr[2 * tid + 1];
    } else {
        d = tid - E_EDGES;
        src = d;
        a0 = ea_mean[2 * d + 0];
        a1 = ea_mean[2 * d + 1];
    }
    int pos = row_ptr[d] + atomicAdd(&fill[d], 1);
    int4 r;
    r.x = src;
    r.y = __float_as_int(a0);
    r.z = __float_as_int(a1);
    r.w = 0;
    erec[pos] = r;
}

// ---------------- all conversions in one launch ----------------
__global__ void convall(const float* __restrict__ x,
                        const float* __restrict__ W_l, const float* __restrict__ W_r,
                        const float* __restrict__ W1, const float* __restrict__ W2,
                        const float* __restrict__ in_proj_w, const float* __restrict__ out_proj_w,
                        const float* __restrict__ b_l, const float* __restrict__ b_r,
                        bf16* xb, bf16* wlrb, bf16* w1b, bf16* w2b,
                        bf16* wipb, bf16* wopb, float* blr)
{
    int b = blockIdx.x, t = threadIdx.x;
    if (b < 8192) {                      // x copy (float4)
        int i = b * 256 + t;
        store4(&xb[i * 4], *(const float4*)&x[i * 4]);
    } else if (b < 8448) {               // W_l [256][256] -> wlrb rows 0..255 [n][k]
        int i = (b - 8192) * 256 + t; int k = i >> 8, n = i & 255;
        wlrb[n * 256 + k] = f2bf(W_l[i]);
    } else if (b < 8704) {               // W_r -> wlrb rows 256..511
        int i = (b - 8448) * 256 + t; int k = i >> 8, n = i & 255;
        wlrb[(256 + n) * 256 + k] = f2bf(W_r[i]);
    } else if (b < 9728) {               // W1 [256][1024] -> w1b[n*256+k]
        int i = (b - 8704) * 256 + t; int k = i >> 10, n = i & 1023;
        w1b[n * 256 + k] = f2bf(W1[i]);
    } else if (b < 10752) {              // W2 [1024][256] -> w2b[n*1024+k]
        int i = (b - 9728) * 256 + t; int k = i >> 8, n = i & 255;
        w2b[n * 1024 + k] = f2bf(W2[i]);
    } else if (b < 10944) {              // in_proj_w [768][256] straight copy ([n][k])
        int i = (b - 10752) * 256 + t;
        store4(&wipb[i * 4], *(const float4*)&in_proj_w[i * 4]);
    } else if (b < 11008) {              // out_proj_w [256][256] straight copy
        int i = (b - 10944) * 256 + t;
        store4(&wopb[i * 4], *(const float4*)&out_proj_w[i * 4]);
    } else {                             // concat biases
        blr[t] = b_l[t]; blr[256 + t] = b_r[t];
    }
}

// ---------------- MFMA bf16 GEMM (m97-style staging) ----------------
// C[m][n] = A[m][k] * Wb[n][k]^T + bias (+gelu|+res|dual-split).
// EPI: 0 bias, 1 bias+gelu, 2 bias+residual, 3 split N=512 -> C(gn<256), res(gn>=256)
template <int EPI>
__global__ __launch_bounds__(256) void mfma_gemm(
    const bf16* __restrict__ A, const bf16* __restrict__ Wb,
    const float* __restrict__ bias, const bf16* __restrict__ res,
    bf16* __restrict__ C, int M, int N, int K)
{
    __shared__ bf16 lds[2 * 128 * 64];   // 32 KiB, unpadded (required by global_load_lds)
    bf16* As = lds;
    bf16* Bs = lds + 128 * 64;
    int tid = threadIdx.x;
    int wave = tid >> 6, lane = tid & 63;
    int quad = lane >> 4, l16 = lane & 15;
    int n0 = blockIdx.x * 128, m0 = blockIdx.y * 128;
    int wm = (wave & 1) * 64, wn = (wave >> 1) * 64;

    f4 acc[4][4] = {};

    int srow = tid >> 3;            // 0..31 base row
    int scol = (tid & 7) * 8;       // k-offset in bf16 elems (16B chunks)

    for (int k0 = 0; k0 < K; k0 += 64) {
        #pragma unroll
        for (int i = 0; i < 4; i++) {
            int row = i * 32 + srow;
            cp16(&A[(size_t)(m0 + row) * K + k0 + scol], &As[row * 64 + scol]);
            cp16(&Wb[(size_t)(n0 + row) * K + k0 + scol], &Bs[row * 64 + scol]);
        }
        __syncthreads();
        #pragma unroll
        for (int ks = 0; ks < 2; ks++) {
            short8 af[4], bfr[4];
            #pragma unroll
            for (int mt = 0; mt < 4; mt++)
                af[mt] = *(const short8*)&As[(wm + mt * 16 + l16) * 64 + ks * 32 + quad * 8];
            #pragma unroll
            for (int nt = 0; nt < 4; nt++)
                bfr[nt] = *(const short8*)&Bs[(wn + nt * 16 + l16) * 64 + ks * 32 + quad * 8];
            #pragma unroll
            for (int mt = 0; mt < 4; mt++)
                #pragma unroll
                for (int nt = 0; nt < 4; nt++)
                    acc[mt][nt] = __builtin_amdgcn_mfma_f32_16x16x32_bf16(
                        af[mt], bfr[nt], acc[mt][nt], 0, 0, 0);
        }
        __syncthreads();
    }

    // epilogue: per-wave LDS transpose for coalesced bf16 stores
    float* epi = (float*)lds + wave * 16 * 68;
    int row = lane >> 2;
    int cb = (lane & 3) * 16;
    int gn = n0 + wn + cb;
    float bb[16];
    *(float4*)&bb[0]  = *(const float4*)&bias[gn + 0];
    *(float4*)&bb[4]  = *(const float4*)&bias[gn + 4];
    *(float4*)&bb[8]  = *(const float4*)&bias[gn + 8];
    *(float4*)&bb[12] = *(const float4*)&bias[gn + 12];

    for (int mt = 0; mt < 4; mt++) {
        #pragma unroll
        for (int nt = 0; nt < 4; nt++)
            #pragma unroll
            for (int r = 0; r < 4; r++)
                epi[(quad * 4 + r) * 68 + nt * 16 + l16] = acc[mt][nt][r];
        float vv[16];
        *(float4*)&vv[0]  = *(float4*)&epi[row * 68 + cb + 0];
        *(float4*)&vv[4]  = *(float4*)&epi[row * 68 + cb + 4];
        *(float4*)&vv[8]  = *(float4*)&epi[row * 68 + cb + 8];
        *(float4*)&vv[12] = *(float4*)&epi[row * 68 + cb + 12];
        int gm = m0 + wm + mt * 16 + row;
        #pragma unroll
        for (int j = 0; j < 16; j++) vv[j] += bb[j];
        if (EPI == 1) {
            #pragma unroll
            for (int j = 0; j < 16; j++)
                vv[j] = 0.5f * vv[j] * (1.0f + erff(vv[j] * 0.70710678118654752f));
        } else if (EPI == 2) {
            ushort rr[16];
            const bf16* rp = &res[(size_t)gm * N + gn];
            *(int4*)&rr[0] = *(const int4*)&rp[0];
            *(int4*)&rr[8] = *(const int4*)&rp[8];
            #pragma unroll
            for (int j = 0; j < 16; j++) vv[j] += bf2f(rr[j]);
        }
        ushort o16[16];
        #pragma unroll
        for (int j = 0; j < 16; j++) o16[j] = f2bf(vv[j]);
        bf16* cp;
        if (EPI == 3) {
            bf16* dst = (gn < 256) ? C : (bf16*)res;
            int goff = (gn < 256) ? gn : gn - 256;
            cp = &dst[(size_t)gm * 256 + goff];
        } else {
            cp = &C[(size_t)gm * N + gn];
        }
        *(int4*)&cp[0] = *(int4*)&o16[0];
        *(int4*)&cp[8] = *(int4*)&o16[8];
    }
}

// ---------------- MFMA flash attention v1 (best measured; interleaved qkv) ----
__global__ __launch_bounds__(256) void attn_mfma(
    const bf16* __restrict__ qkv, bf16* __restrict__ attnout)
{
    __shared__ bf16 Ks[128 * 40];      // [key][k], stride 40
    __shared__ bf16 Vt[32 * 136];      // [d][key], stride 136
    __shared__ bf16 Pb[4 * 64 * 40];   // per-wave [q][key], stride 40

    int b = blockIdx.x;                // 1024 = g*16 + h*2 + half
    int g = b >> 4, h = (b >> 1) & 7, hlf = b & 1;
    int tid = threadIdx.x;
    int wave = tid >> 6, lane = tid & 63;
    int quad = lane >> 4, l16 = lane & 15;
    int qbase = hlf * 256 + wave * 64;
    bf16* Pw = &Pb[wave * 64 * 40];
    const float SCALE = 0.17677669529663687f;

    short8 qf[4];
    #pragma unroll
    for (int mt = 0; mt < 4; mt++) {
        size_t node = (size_t)(g * NPG + qbase + mt * 16 + l16);
        qf[mt] = *(const short8*)&qkv[node * 768 + h * CDIM + quad * 8];
    }

    f4 oacc[4][2] = {};
    float lacc[4][4] = {};

    for (int c = 0; c < 4; c++) {
        int kk0 = c * 128;
        __syncthreads();
        #pragma unroll
        for (int i = 0; i < 2; i++) {
            int idx = i * 256 + tid;
            int key = idx >> 2, kc = (idx & 3) * 8;
            *(int4*)&Ks[key * 40 + kc] =
                *(const int4*)&qkv[(size_t)(g * NPG + kk0 + key) * 768 + 256 + h * CDIM + kc];
        }
        {
            int key = tid >> 1, dblk = (tid & 1) * 16;
            ushort tmp[16];
            const bf16* vp = &qkv[(size_t)(g * NPG + kk0 + key) * 768 + 512 + h * CDIM + dblk];
            *(int4*)&tmp[0] = *(const int4*)&vp[0];
            *(int4*)&tmp[8] = *(const int4*)&vp[8];
            #pragma unroll
            for (int j = 0; j < 16; j++) Vt[(dblk + j) * 136 + key] = tmp[j];
        }
        __syncthreads();

        for (int sub = 0; sub < 4; sub++) {
            int ks0 = sub * 32;
            short8 kf[2];
            #pragma unroll
            for (int nt = 0; nt < 2; nt++)
                kf[nt] = *(const short8*)&Ks[(ks0 + nt * 16 + l16) * 40 + quad * 8];
            #pragma unroll
            for (int mt = 0; mt < 4; mt++) {
                #pragma unroll
                for (int nt = 0; nt < 2; nt++) {
                    f4 z = {0.f, 0.f, 0.f, 0.f};
                    f4 s = __builtin_amdgcn_mfma_f32_16x16x32_bf16(qf[mt], kf[nt], z, 0, 0, 0);
                    #pragma unroll
                    for (int r = 0; r < 4; r++) {
                        float p = __expf(s[r] * SCALE);
                        lacc[mt][r] += p;
                        Pw[(mt * 16 + quad * 4 + r) * 40 + nt * 16 + l16] = f2bf(p);
                    }
                }
            }
            short8 vf[2];
            #pragma unroll
            for (int dt = 0; dt < 2; dt++)
                vf[dt] = *(const short8*)&Vt[(dt * 16 + l16) * 136 + ks0 + quad * 8];
            #pragma unroll
            for (int mt = 0; mt < 4; mt++) {
                short8 pf = *(const short8*)&Pw[(mt * 16 + l16) * 40 + quad * 8];
                #pragma unroll
                for (int dt = 0; dt < 2; dt++)
                    oacc[mt][dt] = __builtin_amdgcn_mfma_f32_16x16x32_bf16(
                        pf, vf[dt], oacc[mt][dt], 0, 0, 0);
            }
        }
    }

    #pragma unroll
    for (int mt = 0; mt < 4; mt++)
        #pragma unroll
        for (int r = 0; r < 4; r++) {
            float l = lacc[mt][r];
            l += __shfl_xor(l, 1);
            l += __shfl_xor(l, 2);
            l += __shfl_xor(l, 4);
            l += __shfl_xor(l, 8);
            lacc[mt][r] = l;
        }

    #pragma unroll
    for (int mt = 0; mt < 4; mt++) {
        #pragma unroll
        for (int dt = 0; dt < 2; dt++) {
            #pragma unroll
            for (int r = 0; r < 4; r++) {
                float v = oacc[mt][dt][r] / lacc[mt][r];
                size_t node = (size_t)(g * NPG + qbase + mt * 16 + quad * 4 + r);
                attnout[node * HIDDEN + h * CDIM + dt * 16 + l16] = f2bf(v);
            }
        }
    }
}

// ---------------- GATv2: 2 waves/node + pipeline + packed edge records ----
__device__ __forceinline__ void fetchrec(
    int i, int re, int node, const int4* __restrict__ erec,
    int& s, float& a0, float& a1)
{
    if (i < re) {
        int4 r = erec[i];
        s = r.x; a0 = __int_as_float(r.y); a1 = __int_as_float(r.z);
    } else {
        s = node; a0 = 0.f; a1 = 0.f;
    }
}

__global__ __launch_bounds__(256) void gat_kernel(
    const bf16* __restrict__ xl, const bf16* __restrict__ xr,
    const int* __restrict__ row_ptr, const int4* __restrict__ erec,
    const float* __restrict__ W_e, const float* __restrict__ att,
    const float* __restrict__ bias_gat,
    const float* __restrict__ g1, const float* __restrict__ be1,
    bf16* __restrict__ out)
{
    __shared__ float pacc[2][260];
    __shared__ float plsum[2][64];
    int wave = threadIdx.x >> 6;
    int lane = threadIdx.x & 63;
    int nloc = wave >> 1, half = wave & 1;
    int node = blockIdx.x * 2 + nloc;
    int cb = lane * 4;

    float4 xr4 = load4(&xr[(size_t)node * 256 + cb]);
    float4 we0 = *(const float4*)&W_e[cb];
    float4 we1 = *(const float4*)&W_e[HIDDEN + cb];
    float4 at4 = *(const float4*)&att[cb];

    int rs = row_ptr[node], re = row_ptr[node + 1];

    float lsum = 0.f;
    float acc0 = 0.f, acc1 = 0.f, acc2 = 0.f, acc3 = 0.f;

    int i0 = rs + half;
    int s0, s1; float a00, a01, a10, a11;
    fetchrec(i0,     re, node, erec, s0, a00, a01);
    fetchrec(i0 + 2, re, node, erec, s1, a10, a11);
    ushort4 xu0 = *(const ushort4*)&xl[(size_t)s0 * 256 + cb];

    for (int i = i0; i < re; i += 2) {
        int s2; float a20, a21;
        fetchrec(i + 4, re, node, erec, s2, a20, a21);
        ushort4 xu1 = *(const ushort4*)&xl[(size_t)s1 * 256 + cb];

        float4 xl4 = make_float4(bf2f(xu0.x), bf2f(xu0.y), bf2f(xu0.z), bf2f(xu0.w));
        float t, p = 0.f;
        t = xl4.x + xr4.x + a00 * we0.x + a01 * we1.x; t = (t > 0.f) ? t : 0.2f * t; p += t * at4.x;
        t = xl4.y + xr4.y + a00 * we0.y + a01 * we1.y; t = (t > 0.f) ? t : 0.2f * t; p += t * at4.y;
        t = xl4.z + xr4.z + a00 * we0.z + a01 * we1.z; t = (t > 0.f) ? t : 0.2f * t; p += t * at4.z;
        t = xl4.w + xr4.w + a00 * we0.w + a01 * we1.w; t = (t > 0.f) ? t : 0.2f * t; p += t * at4.w;
        p += __shfl_xor(p, 1);
        p += __shfl_xor(p, 2);
        p += __shfl_xor(p, 4);
        float w = __expf(p);
        lsum += w;
        acc0 += w * xl4.x; acc1 += w * xl4.y; acc2 += w * xl4.z; acc3 += w * xl4.w;

        s0 = s1; a00 = a10; a01 = a11; xu0 = xu1;
        s1 = s2; a10 = a20; a11 = a21;
    }

    if (half) {
        plsum[nloc][lane] = lsum;
        pacc[nloc][cb + 0] = acc0; pacc[nloc][cb + 1] = acc1;
        pacc[nloc][cb + 2] = acc2; pacc[nloc][cb + 3] = acc3;
    }
    __syncthreads();
    if (!half) {
        lsum += plsum[nloc][lane];
        acc0 += pacc[nloc][cb + 0]; acc1 += pacc[nloc][cb + 1];
        acc2 += pacc[nloc][cb + 2]; acc3 += pacc[nloc][cb + 3];

        float inv = 1.0f / lsum;
        float v0 = acc0 * inv + bias_gat[cb + 0];
        float v1 = acc1 * inv + bias_gat[cb + 1];
        float v2 = acc2 * inv + bias_gat[cb + 2];
        float v3 = acc3 * inv + bias_gat[cb + 3];

        float s = v0 + v1 + v2 + v3;
        #pragma unroll
        for (int m = 1; m < 64; m <<= 1) s += __shfl_xor(s, m);
        float mean = s * (1.0f / 256.0f);
        float d0 = v0 - mean, d1 = v1 - mean, d2 = v2 - mean, d3 = v3 - mean;
        float sq = d0 * d0 + d1 * d1 + d2 * d2 + d3 * d3;
        #pragma unroll
        for (int m = 1; m < 64; m <<= 1) sq += __shfl_xor(sq, m);
        float rstd = rsqrtf(sq * (1.0f / 256.0f) + 1e-5f);
        float4 o;
        o.x = d0 * rstd * g1[cb + 0] + be1[cb + 0];
        o.y = d1 * rstd * g1[cb + 1] + be1[cb + 1];
        o.z = d2 * rstd * g1[cb + 2] + be1[cb + 2];
        o.w = d3 * rstd * g1[cb + 3] + be1[cb + 3];
        store4(&out[(size_t)node * HIDDEN + cb], o);
    }
}

// ---------------- LN2(gout) + gated combine ----------------
__global__ __launch_bounds__(256) void combine_kernel(
    const bf16* __restrict__ gout, const bf16* __restrict__ localout,
    const float* __restrict__ alpha_p,
    const float* __restrict__ g2, const float* __restrict__ be2,
    bf16* __restrict__ combined)
{
    int wave = threadIdx.x >> 6;
    int lane = threadIdx.x & 63;
    int node = blockIdx.x * 4 + wave;
    int cb = lane * 4;
    float4 gv = load4(&gout[(size_t)node * HIDDEN + cb]);
    float s = gv.x + gv.y + gv.z + gv.w;
    #pragma unroll
    for (int m = 1; m < 64; m <<= 1) s += __shfl_xor(s, m);
    float mean = s * (1.0f / 256.0f);
    float d0 = gv.x - mean, d1 = gv.y - mean, d2 = gv.z - mean, d3 = gv.w - mean;
    float sq = d0 * d0 + d1 * d1 + d2 * d2 + d3 * d3;
    #pragma unroll
    for (int m = 1; m < 64; m <<= 1) sq += __shfl_xor(sq, m);
    float rstd = rsqrtf(sq * (1.0f / 256.0f) + 1e-5f);
    float n0 = d0 * rstd * g2[cb + 0] + be2[cb + 0];
    float n1 = d1 * rstd * g2[cb + 1] + be2[cb + 1];
    float n2 = d2 * rstd * g2[cb + 2] + be2[cb + 2];
    float n3 = d3 * rstd * g2[cb + 3] + be2[cb + 3];
    float a = 1.0f / (1.0f + __expf(-alpha_p[0]));
    float4 lv = load4(&localout[(size_t)node * HIDDEN + cb]);
    float4 o;
    o.x = a * lv.x + (1.0f - a) * n0;
    o.y = a * lv.y + (1.0f - a) * n1;
    o.z = a * lv.z + (1.0f - a) * n2;
    o.w = a * lv.w + (1.0f - a) * n3;
    store4(&combined[(size_t)node * HIDDEN + cb], o);
}

// ---------------- final LN3 ----------------
__global__ __launch_bounds__(256) void finalln_kernel(
    const bf16* __restrict__ ffn,
    const float* __restrict__ g3, const float* __restrict__ be3,
    float* __restrict__ out)
{
    int wave = threadIdx.x >> 6;
    int lane = threadIdx.x & 63;
    int node = blockIdx.x * 4 + wave;
    int cb = lane * 4;
    float4 v = load4(&ffn[(size_t)node * HIDDEN + cb]);
    float s = v.x + v.y + v.z + v.w;
    #pragma unroll
    for (int m = 1; m < 64; m <<= 1) s += __shfl_xor(s, m);
    float mean = s * (1.0f / 256.0f);
    float d0 = v.x - mean, d1 = v.y - mean, d2 = v.z - mean, d3 = v.w - mean;
    float sq = d0 * d0 + d1 * d1 + d2 * d2 + d3 * d3;
    #pragma unroll
    for (int m = 1; m < 64; m <<= 1) sq += __shfl_xor(sq, m);
    float rstd = rsqrtf(sq * (1.0f / 256.0f) + 1e-5f);
    float4 o;
    o.x = d0 * rstd * g3[cb + 0] + be3[cb + 0];
    o.y = d1 * rstd * g3[cb + 1] + be3[cb + 1];
    o.z = d2 * rstd * g3[cb + 2] + be3[cb + 2];
    o.w = d3 * rstd * g3[cb + 3] + be3[cb + 3];
    *(float4*)&out[(size_t)node * HIDDEN + cb] = o;
}

// ---------------- launch ----------------
extern "C" void kernel_launch(void* const* d_in, const int* in_sizes, int n_in,
                              void* d_out, int out_size, void* d_ws, size_t ws_size,
                              hipStream_t stream) {
    const float* x          = (const float*)d_in[0];
    const float* edge_attr  = (const float*)d_in[1];
    const float* W_l        = (const float*)d_in[2];
    const float* b_l        = (const float*)d_in[3];
    const float* W_r        = (const float*)d_in[4];
    const float* b_r        = (const float*)d_in[5];
    const float* W_e        = (const float*)d_in[6];
    const float* att        = (const float*)d_in[7];
    const float* bias_gat   = (const float*)d_in[8];
    const float* in_proj_w  = (const float*)d_in[9];
    const float* in_proj_b  = (const float*)d_in[10];
    const float* out_proj_w = (const float*)d_in[11];
    const float* out_proj_b = (const float*)d_in[12];
    const float* alpha_p    = (const float*)d_in[13];
    const float* W1         = (const float*)d_in[14];
    const float* b1         = (const float*)d_in[15];
    const float* W2         = (const float*)d_in[16];
    const float* b2         = (const float*)d_in[17];
    const float* g1  = (const float*)d_in[18];
    const float* be1 = (const float*)d_in[19];
    const float* g2  = (const float*)d_in[20];
    const float* be2 = (const float*)d_in[21];
    const float* g3  = (const float*)d_in[22];
    const float* be3 = (const float*)d_in[23];
    const int* edge_index = (const int*)d_in[24];

    char* base = (char*)d_ws;
    const size_t MB = 1024 * 1024;
    const size_t KB = 1024;
    // graph prep [0, 3 MiB)
    float* deg     = (float*)(base + 0);
    float* ea_mean = (float*)(base + 131072);
    int*   fill    = (int*)  (base + 393216);
    int*   row_ptr = (int*)  (base + 524288);
    // bf16 weights [3 MiB, ~5 MiB)
    bf16* wlrb = (bf16*)(base + 3 * MB);              // 512x256  (256 KB)
    bf16* wipb = (bf16*)(base + 3 * MB + 256 * KB);   // 768x256  (384 KB)
    bf16* wopb = (bf16*)(base + 3 * MB + 640 * KB);   // 256x256  (128 KB)
    bf16* w1b  = (bf16*)(base + 3 * MB + 768 * KB);   // 1024x256 (512 KB)
    bf16* w2b  = (bf16*)(base + 3 * MB + 1280 * KB);  // 256x1024 (512 KB)
    float* blr = (float*)(base + 5 * MB);             // 512 floats
    // big bf16 buffers (aliased; peak 88 MiB) + erec [88, ~96.6)
    bf16* xb       = (bf16*)(base + 8 * MB);    // [8,24)
    bf16* qkv      = (bf16*)(base + 24 * MB);   // [24,72)
    bf16* attnout  = (bf16*)(base + 72 * MB);   // [72,88)
    bf16* gout     = (bf16*)(base + 24 * MB);   // [24,40)  (qkv dead)
    bf16* xl       = (bf16*)(base + 40 * MB);   // [40,56)  (qkv dead) [N][256]
    bf16* xr       = (bf16*)(base + 56 * MB);   // [56,72)  [N][256]
    bf16* localout = (bf16*)(base + 72 * MB);   // [72,88)  (attnout dead)
    bf16* combined = (bf16*)(base + 8 * MB);    // [8,24)   (xb dead)
    bf16* h1h      = (bf16*)(base + 24 * MB);   // [24,56)  (gout/xl dead)
    bf16* ffn      = (bf16*)(base + 56 * MB);   // [56,72)  (xr dead)
    int4* erec     = (int4*)(base + 88 * MB);   // [88, 96.6)  (E+N)*16B
    float* out = (float*)d_out;

    // ---- GAT graph prep ----
    zero_kernel<<<(2 * N_NODES + 255) / 256, 256, 0, stream>>>(deg, ea_mean, fill);
    deg_kernel<<<E_EDGES / 256, 256, 0, stream>>>(edge_index, edge_attr, deg, ea_mean);
    eamean_kernel<<<N_NODES / 256, 256, 0, stream>>>(deg, ea_mean);
    scan_kernel<<<1, 1024, 0, stream>>>(deg, row_ptr);
    fill_kernel<<<(E_EDGES + N_NODES + 255) / 256, 256, 0, stream>>>(
        edge_index, edge_attr, ea_mean, row_ptr, fill, erec);

    // ---- conversions (single launch) ----
    convall<<<11009, 256, 0, stream>>>(x, W_l, W_r, W1, W2, in_proj_w, out_proj_w,
                                       b_l, b_r, xb, wlrb, w1b, w2b, wipb, wopb, blr);

    // ---- MHA path first ----
    mfma_gemm<0><<<dim3(6, 256), 256, 0, stream>>>(
        xb, wipb, in_proj_b, (const bf16*)nullptr, qkv, N_NODES, 768, 256);
    attn_mfma<<<NGRAPH * NHEAD * 2, 256, 0, stream>>>(qkv, attnout);
    mfma_gemm<0><<<dim3(2, 256), 256, 0, stream>>>(
        attnout, wopb, out_proj_b, (const bf16*)nullptr, gout, N_NODES, 256, 256);

    // ---- GAT path (fused xl|xr GEMM, dual split output) ----
    mfma_gemm<3><<<dim3(4, 256), 256, 0, stream>>>(
        xb, wlrb, blr, (const bf16*)xr, xl, N_NODES, 512, 256);
    gat_kernel<<<N_NODES / 2, 256, 0, stream>>>(
        xl, xr, row_ptr, erec, W_e, att, bias_gat, g1, be1, localout);

    // ---- LN2 + gated combine ----
    combine_kernel<<<N_NODES / 4, 256, 0, stream>>>(
        gout, localout, alpha_p, g2, be2, combined);

    // ---- FFN in two M-halves ----
    for (int hh = 0; hh < 2; hh++) {
        const bf16* ch = combined + (size_t)hh * 16384 * 256;
        bf16* fh = ffn + (size_t)hh * 16384 * 256;
        mfma_gemm<1><<<dim3(8, 128), 256, 0, stream>>>(
            ch, w1b, b1, (const bf16*)nullptr, h1h, 16384, 1024, 256);
        mfma_gemm<2><<<dim3(2, 128), 256, 0, stream>>>(
            h1h, w2b, b2, ch, fh, 16384, 256, 1024);
    }

    // ---- LN3 -> out ----
    finalln_kernel<<<N_NODES / 4, 256, 0, stream>>>(ffn, g3, be3, out);
}

// Round 9
// 588.483 us; speedup vs baseline: 1.1625x; 1.0038x over previous
//
#include <hip/hip_runtime.h>
#include <math.h>

#define N_NODES 32768
#define E_EDGES 524288
#define HIDDEN  256
#define NPG     512
#define NGRAPH  64
#define NHEAD   8
#define CDIM    32

typedef unsigned short bf16;
typedef __attribute__((ext_vector_type(8))) short short8;
typedef __attribute__((ext_vector_type(4))) float f4;

#define AS1 __attribute__((address_space(1)))
#define AS3 __attribute__((address_space(3)))

__device__ __forceinline__ void cp16(const bf16* g, bf16* l) {
    __builtin_amdgcn_global_load_lds((AS1 const unsigned int*)(const void*)g,
                                     (AS3 unsigned int*)(void*)l, 16, 0, 0);
}

// ---------------- bf16 helpers ----------------
__device__ inline float bf2f(unsigned short u) {
    union { unsigned int i; float f; } v; v.i = ((unsigned int)u) << 16; return v.f;
}
__device__ inline unsigned short f2bf(float f) {
    union { float f; unsigned int i; } v; v.f = f;
    unsigned int x = v.i;
    return (unsigned short)((x + 0x7FFFu + ((x >> 16) & 1u)) >> 16);
}
__device__ inline unsigned short f2bf_trunc(float f) {
    return (unsigned short)(__float_as_uint(f) >> 16);
}
__device__ inline float4 load4(const float* p) { return *(const float4*)p; }
__device__ inline float4 load4(const bf16* p) {
    ushort4 u = *(const ushort4*)p;
    return make_float4(bf2f(u.x), bf2f(u.y), bf2f(u.z), bf2f(u.w));
}
__device__ inline void store4(float* p, float4 v) { *(float4*)p = v; }
__device__ inline void store4(bf16* p, float4 v) {
    ushort4 u; u.x = f2bf(v.x); u.y = f2bf(v.y); u.z = f2bf(v.z); u.w = f2bf(v.w);
    *(ushort4*)p = u;
}

// ---------------- small utility kernels ----------------

__global__ void zero_kernel(float* deg, float* ea_sum, int* fill) {
    int i = blockIdx.x * blockDim.x + threadIdx.x;
    if (i < 2 * N_NODES) ea_sum[i] = 0.0f;
    if (i < N_NODES) { deg[i] = 0.0f; fill[i] = 0; }
}

__global__ void deg_kernel(const int* __restrict__ ei, const float* __restrict__ edge_attr,
                           float* deg, float* ea_sum) {
    int e = blockIdx.x * blockDim.x + threadIdx.x;
    if (e >= E_EDGES) return;
    int d = ei[E_EDGES + e];
    atomicAdd(&deg[d], 1.0f);
    atomicAdd(&ea_sum[2 * d + 0], edge_attr[2 * e + 0]);
    atomicAdd(&ea_sum[2 * d + 1], edge_attr[2 * e + 1]);
}

__global__ __launch_bounds__(1024) void scan_kernel(const float* __restrict__ deg, int* row_ptr) {
    __shared__ int part[1024];
    int t = threadIdx.x;
    int base = t * 32;
    int loc[32];
    int s = 0;
    #pragma unroll
    for (int j = 0; j < 32; j++) {
        loc[j] = s;
        s += (int)deg[base + j] + 1;
    }
    int mysum = s;
    part[t] = s;
    __syncthreads();
    for (int off = 1; off < 1024; off <<= 1) {
        int v = 0;
        if (t >= off) v = part[t - off];
        __syncthreads();
        part[t] += v;
        __syncthreads();
    }
    int offset = part[t] - mysum;
    #pragma unroll
    for (int j = 0; j < 32; j++) row_ptr[base + j] = offset + loc[j];
    if (t == 1023) row_ptr[N_NODES] = part[1023];
}

// CSR fill with PACKED 16B edge records: {src, ea0, ea1, 0}; self-loop mean inline
__global__ void fill_kernel(const int* __restrict__ ei, const float* __restrict__ edge_attr,
                            const float* __restrict__ ea_sum, const float* __restrict__ deg,
                            const int* __restrict__ row_ptr, int* fill, int4* __restrict__ erec) {
    int tid = blockIdx.x * blockDim.x + threadIdx.x;
    if (tid >= E_EDGES + N_NODES) return;
    int d, src; float a0, a1;
    if (tid < E_EDGES) {
        d = ei[E_EDGES + tid];
        src = ei[tid];
        a0 = edge_attr[2 * tid + 0];
        a1 = edge_attr[2 * tid + 1];
    } else {
        d = tid - E_EDGES;
        src = d;
        float dm = fmaxf(deg[d], 1.0f);
        a0 = ea_sum[2 * d + 0] / dm;
        a1 = ea_sum[2 * d + 1] / dm;
    }
    int pos = row_ptr[d] + atomicAdd(&fill[d], 1);
    int4 r;
    r.x = src;
    r.y = __float_as_int(a0);
    r.z = __float_as_int(a1);
    r.w = 0;
    erec[pos] = r;
}

// ---------------- all conversions in one launch ----------------
// q-slab of in_proj (rows 0..255) pre-scaled by SCALE*log2(e) so attn uses exp2.
#define QSCALE 0.25506882685716462f
__global__ void convall(const float* __restrict__ x,
                        const float* __restrict__ W_l, const float* __restrict__ W_r,
                        const float* __restrict__ W1, const float* __restrict__ W2,
                        const float* __restrict__ in_proj_w, const float* __restrict__ out_proj_w,
                        const float* __restrict__ b_l, const float* __restrict__ b_r,
                        const float* __restrict__ in_proj_b,
                        bf16* xb, bf16* wlrb, bf16* w1b, bf16* w2b,
                        bf16* wipb, bf16* wopb, float* blr, float* ipb2)
{
    int b = blockIdx.x, t = threadIdx.x;
    if (b < 8192) {                      // x copy (float4)
        int i = b * 256 + t;
        store4(&xb[i * 4], *(const float4*)&x[i * 4]);
    } else if (b < 8448) {               // W_l [256][256] -> wlrb rows 0..255 [n][k]
        int i = (b - 8192) * 256 + t; int k = i >> 8, n = i & 255;
        wlrb[n * 256 + k] = f2bf(W_l[i]);
    } else if (b < 8704) {               // W_r -> wlrb rows 256..511
        int i = (b - 8448) * 256 + t; int k = i >> 8, n = i & 255;
        wlrb[(256 + n) * 256 + k] = f2bf(W_r[i]);
    } else if (b < 9728) {               // W1 [256][1024] -> w1b[n*256+k]
        int i = (b - 8704) * 256 + t; int k = i >> 10, n = i & 1023;
        w1b[n * 256 + k] = f2bf(W1[i]);
    } else if (b < 10752) {              // W2 [1024][256] -> w2b[n*1024+k]
        int i = (b - 9728) * 256 + t; int k = i >> 8, n = i & 255;
        w2b[n * 1024 + k] = f2bf(W2[i]);
    } else if (b < 10944) {              // in_proj_w [768][256] copy; q rows scaled
        int i = (b - 10752) * 256 + t;
        float4 v = *(const float4*)&in_proj_w[i * 4];
        if (i < 16384) { v.x *= QSCALE; v.y *= QSCALE; v.z *= QSCALE; v.w *= QSCALE; }
        store4(&wipb[i * 4], v);
    } else if (b < 11008) {              // out_proj_w straight
        int i = (b - 10944) * 256 + t;
        store4(&wopb[i * 4], *(const float4*)&out_proj_w[i * 4]);
    } else {                             // biases
        blr[t] = b_l[t]; blr[256 + t] = b_r[t];
        ipb2[t] = in_proj_b[t] * QSCALE;
        ipb2[256 + t] = in_proj_b[256 + t];
        ipb2[512 + t] = in_proj_b[512 + t];
    }
}

// ---------------- MFMA bf16 GEMM (m97-style staging) ----------------
// EPI: 0 bias, 1 bias+gelu, 3 split N=512 -> C(gn<256), res(gn>=256),
//      4 bias+residual(res bf16) -> fp32 store into (float*)C
template <int EPI>
__global__ __launch_bounds__(256) void mfma_gemm(
    const bf16* __restrict__ A, const bf16* __restrict__ Wb,
    const float* __restrict__ bias, const bf16* __restrict__ res,
    bf16* __restrict__ C, int M, int N, int K)
{
    __shared__ bf16 lds[2 * 128 * 64];
    bf16* As = lds;
    bf16* Bs = lds + 128 * 64;
    int tid = threadIdx.x;
    int wave = tid >> 6, lane = tid & 63;
    int quad = lane >> 4, l16 = lane & 15;
    int n0 = blockIdx.x * 128, m0 = blockIdx.y * 128;
    int wm = (wave & 1) * 64, wn = (wave >> 1) * 64;

    f4 acc[4][4] = {};
    int srow = tid >> 3;
    int scol = (tid & 7) * 8;

    for (int k0 = 0; k0 < K; k0 += 64) {
        #pragma unroll
        for (int i = 0; i < 4; i++) {
            int row = i * 32 + srow;
            cp16(&A[(size_t)(m0 + row) * K + k0 + scol], &As[row * 64 + scol]);
            cp16(&Wb[(size_t)(n0 + row) * K + k0 + scol], &Bs[row * 64 + scol]);
        }
        __syncthreads();
        #pragma unroll
        for (int ks = 0; ks < 2; ks++) {
            short8 af[4], bfr[4];
            #pragma unroll
            for (int mt = 0; mt < 4; mt++)
                af[mt] = *(const short8*)&As[(wm + mt * 16 + l16) * 64 + ks * 32 + quad * 8];
            #pragma unroll
            for (int nt = 0; nt < 4; nt++)
                bfr[nt] = *(const short8*)&Bs[(wn + nt * 16 + l16) * 64 + ks * 32 + quad * 8];
            #pragma unroll
            for (int mt = 0; mt < 4; mt++)
                #pragma unroll
                for (int nt = 0; nt < 4; nt++)
                    acc[mt][nt] = __builtin_amdgcn_mfma_f32_16x16x32_bf16(
                        af[mt], bfr[nt], acc[mt][nt], 0, 0, 0);
        }
        __syncthreads();
    }

    float* epi = (float*)lds + wave * 16 * 68;
    int row = lane >> 2;
    int cb = (lane & 3) * 16;
    int gn = n0 + wn + cb;
    float bb[16];
    *(float4*)&bb[0]  = *(const float4*)&bias[gn + 0];
    *(float4*)&bb[4]  = *(const float4*)&bias[gn + 4];
    *(float4*)&bb[8]  = *(const float4*)&bias[gn + 8];
    *(float4*)&bb[12] = *(const float4*)&bias[gn + 12];

    for (int mt = 0; mt < 4; mt++) {
        #pragma unroll
        for (int nt = 0; nt < 4; nt++)
            #pragma unroll
            for (int r = 0; r < 4; r++)
                epi[(quad * 4 + r) * 68 + nt * 16 + l16] = acc[mt][nt][r];
        float vv[16];
        *(float4*)&vv[0]  = *(float4*)&epi[row * 68 + cb + 0];
        *(float4*)&vv[4]  = *(float4*)&epi[row * 68 + cb + 4];
        *(float4*)&vv[8]  = *(float4*)&epi[row * 68 + cb + 8];
        *(float4*)&vv[12] = *(float4*)&epi[row * 68 + cb + 12];
        int gm = m0 + wm + mt * 16 + row;
        #pragma unroll
        for (int j = 0; j < 16; j++) vv[j] += bb[j];
        if (EPI == 1) {
            #pragma unroll
            for (int j = 0; j < 16; j++)
                vv[j] = 0.5f * vv[j] * (1.0f + erff(vv[j] * 0.70710678118654752f));
        } else if (EPI == 4) {
            ushort rr[16];
            const bf16* rp = &res[(size_t)gm * N + gn];
            *(int4*)&rr[0] = *(const int4*)&rp[0];
            *(int4*)&rr[8] = *(const int4*)&rp[8];
            #pragma unroll
            for (int j = 0; j < 16; j++) vv[j] += bf2f(rr[j]);
            float* cf = (float*)C + (size_t)gm * N + gn;
            *(float4*)&cf[0]  = *(float4*)&vv[0];
            *(float4*)&cf[4]  = *(float4*)&vv[4];
            *(float4*)&cf[8]  = *(float4*)&vv[8];
            *(float4*)&cf[12] = *(float4*)&vv[12];
            continue;
        }
        ushort o16[16];
        #pragma unroll
        for (int j = 0; j < 16; j++) o16[j] = f2bf(vv[j]);
        bf16* cp;
        if (EPI == 3) {
            bf16* dst = (gn < 256) ? C : (bf16*)res;
            int goff = (gn < 256) ? gn : gn - 256;
            cp = &dst[(size_t)gm * 256 + goff];
        } else {
            cp = &C[(size_t)gm * N + gn];
        }
        *(int4*)&cp[0] = *(int4*)&o16[0];
        *(int4*)&cp[8] = *(int4*)&o16[8];
    }
}

// ---------------- MFMA flash attention (q prescaled; exp2; trunc pack) ----
__global__ __launch_bounds__(256) void attn_mfma(
    const bf16* __restrict__ qkv, bf16* __restrict__ attnout)
{
    __shared__ bf16 Ks[128 * 40];
    __shared__ bf16 Vt[32 * 136];
    __shared__ bf16 Pb[4 * 64 * 40];

    int b = blockIdx.x;
    int g = b >> 4, h = (b >> 1) & 7, hlf = b & 1;
    int tid = threadIdx.x;
    int wave = tid >> 6, lane = tid & 63;
    int quad = lane >> 4, l16 = lane & 15;
    int qbase = hlf * 256 + wave * 64;
    bf16* Pw = &Pb[wave * 64 * 40];

    short8 qf[4];
    #pragma unroll
    for (int mt = 0; mt < 4; mt++) {
        size_t node = (size_t)(g * NPG + qbase + mt * 16 + l16);
        qf[mt] = *(const short8*)&qkv[node * 768 + h * CDIM + quad * 8];
    }

    f4 oacc[4][2] = {};
    float lacc[4][4] = {};

    for (int c = 0; c < 4; c++) {
        int kk0 = c * 128;
        __syncthreads();
        #pragma unroll
        for (int i = 0; i < 2; i++) {
            int idx = i * 256 + tid;
            int key = idx >> 2, kc = (idx & 3) * 8;
            *(int4*)&Ks[key * 40 + kc] =
                *(const int4*)&qkv[(size_t)(g * NPG + kk0 + key) * 768 + 256 + h * CDIM + kc];
        }
        {
            int key = tid >> 1, dblk = (tid & 1) * 16;
            ushort tmp[16];
            const bf16* vp = &qkv[(size_t)(g * NPG + kk0 + key) * 768 + 512 + h * CDIM + dblk];
            *(int4*)&tmp[0] = *(const int4*)&vp[0];
            *(int4*)&tmp[8] = *(const int4*)&vp[8];
            #pragma unroll
            for (int j = 0; j < 16; j++) Vt[(dblk + j) * 136 + key] = tmp[j];
        }
        __syncthreads();

        for (int sub = 0; sub < 4; sub++) {
            int ks0 = sub * 32;
            short8 kf[2];
            #pragma unroll
            for (int nt = 0; nt < 2; nt++)
                kf[nt] = *(const short8*)&Ks[(ks0 + nt * 16 + l16) * 40 + quad * 8];
            #pragma unroll
            for (int mt = 0; mt < 4; mt++) {
                #pragma unroll
                for (int nt = 0; nt < 2; nt++) {
                    f4 z = {0.f, 0.f, 0.f, 0.f};
                    f4 s = __builtin_amdgcn_mfma_f32_16x16x32_bf16(qf[mt], kf[nt], z, 0, 0, 0);
                    #pragma unroll
                    for (int r = 0; r < 4; r++) {
                        float p = exp2f(s[r]);     // q prescaled by SCALE*log2e
                        lacc[mt][r] += p;
                        Pw[(mt * 16 + quad * 4 + r) * 40 + nt * 16 + l16] = f2bf_trunc(p);
                    }
                }
            }
            short8 vf[2];
            #pragma unroll
            for (int dt = 0; dt < 2; dt++)
                vf[dt] = *(const short8*)&Vt[(dt * 16 + l16) * 136 + ks0 + quad * 8];
            #pragma unroll
            for (int mt = 0; mt < 4; mt++) {
                short8 pf = *(const short8*)&Pw[(mt * 16 + l16) * 40 + quad * 8];
                #pragma unroll
                for (int dt = 0; dt < 2; dt++)
                    oacc[mt][dt] = __builtin_amdgcn_mfma_f32_16x16x32_bf16(
                        pf, vf[dt], oacc[mt][dt], 0, 0, 0);
            }
        }
    }

    #pragma unroll
    for (int mt = 0; mt < 4; mt++)
        #pragma unroll
        for (int r = 0; r < 4; r++) {
            float l = lacc[mt][r];
            l += __shfl_xor(l, 1);
            l += __shfl_xor(l, 2);
            l += __shfl_xor(l, 4);
            l += __shfl_xor(l, 8);
            lacc[mt][r] = l;
        }

    #pragma unroll
    for (int mt = 0; mt < 4; mt++) {
        #pragma unroll
        for (int dt = 0; dt < 2; dt++) {
            #pragma unroll
            for (int r = 0; r < 4; r++) {
                float v = oacc[mt][dt][r] / lacc[mt][r];
                size_t node = (size_t)(g * NPG + qbase + mt * 16 + quad * 4 + r);
                attnout[node * HIDDEN + h * CDIM + dt * 16 + l16] = f2bf(v);
            }
        }
    }
}

// ---------------- GATv2: 2 waves/node + depth-3 pipeline + packed records ----
__device__ __forceinline__ void fetchrec(
    int i, int re, int node, const int4* __restrict__ erec,
    int& s, float& a0, float& a1)
{
    if (i < re) {
        int4 r = erec[i];
        s = r.x; a0 = __int_as_float(r.y); a1 = __int_as_float(r.z);
    } else {
        s = node; a0 = 0.f; a1 = 0.f;
    }
}

__global__ __launch_bounds__(256) void gat_kernel(
    const bf16* __restrict__ xl, const bf16* __restrict__ xr,
    const int* __restrict__ row_ptr, const int4* __restrict__ erec,
    const float* __restrict__ W_e, const float* __restrict__ att,
    const float* __restrict__ bias_gat,
    const float* __restrict__ g1, const float* __restrict__ be1,
    bf16* __restrict__ out)
{
    __shared__ float pacc[2][260];
    __shared__ float plsum[2][64];
    int wave = threadIdx.x >> 6;
    int lane = threadIdx.x & 63;
    int nloc = wave >> 1, half = wave & 1;
    int node = blockIdx.x * 2 + nloc;
    int cb = lane * 4;

    float4 xr4 = load4(&xr[(size_t)node * 256 + cb]);
    float4 we0 = *(const float4*)&W_e[cb];
    float4 we1 = *(const float4*)&W_e[HIDDEN + cb];
    float4 at4 = *(const float4*)&att[cb];

    int rs = row_ptr[node], re = row_ptr[node + 1];

    float lsum = 0.f;
    float acc0 = 0.f, acc1 = 0.f, acc2 = 0.f, acc3 = 0.f;

    int i0 = rs + half;
    int s0, s1, s2;
    float a00, a01, a10, a11, a20, a21;
    fetchrec(i0,     re, node, erec, s0, a00, a01);
    fetchrec(i0 + 2, re, node, erec, s1, a10, a11);
    fetchrec(i0 + 4, re, node, erec, s2, a20, a21);
    ushort4 xu0 = *(const ushort4*)&xl[(size_t)s0 * 256 + cb];
    ushort4 xu1 = *(const ushort4*)&xl[(size_t)s1 * 256 + cb];

    for (int i = i0; i < re; i += 2) {
        int s3; float a30, a31;
        fetchrec(i + 6, re, node, erec, s3, a30, a31);
        ushort4 xu2 = *(const ushort4*)&xl[(size_t)s2 * 256 + cb];

        float4 xl4 = make_float4(bf2f(xu0.x), bf2f(xu0.y), bf2f(xu0.z), bf2f(xu0.w));
        float t, p = 0.f;
        t = xl4.x + xr4.x + a00 * we0.x + a01 * we1.x; t = (t > 0.f) ? t : 0.2f * t; p += t * at4.x;
        t = xl4.y + xr4.y + a00 * we0.y + a01 * we1.y; t = (t > 0.f) ? t : 0.2f * t; p += t * at4.y;
        t = xl4.z + xr4.z + a00 * we0.z + a01 * we1.z; t = (t > 0.f) ? t : 0.2f * t; p += t * at4.z;
        t = xl4.w + xr4.w + a00 * we0.w + a01 * we1.w; t = (t > 0.f) ? t : 0.2f * t; p += t * at4.w;
        p += __shfl_xor(p, 1);
        p += __shfl_xor(p, 2);
        p += __shfl_xor(p, 4);
        float w = __expf(p);
        lsum += w;
        acc0 += w * xl4.x; acc1 += w * xl4.y; acc2 += w * xl4.z; acc3 += w * xl4.w;

        s0 = s1; a00 = a10; a01 = a11; xu0 = xu1;
        s1 = s2; a10 = a20; a11 = a21; xu1 = xu2;
        s2 = s3; a20 = a30; a21 = a31;
    }

    if (half) {
        plsum[nloc][lane] = lsum;
        pacc[nloc][cb + 0] = acc0; pacc[nloc][cb + 1] = acc1;
        pacc[nloc][cb + 2] = acc2; pacc[nloc][cb + 3] = acc3;
    }
    __syncthreads();
    if (!half) {
        lsum += plsum[nloc][lane];
        acc0 += pacc[nloc][cb + 0]; acc1 += pacc[nloc][cb + 1];
        acc2 += pacc[nloc][cb + 2]; acc3 += pacc[nloc][cb + 3];

        float inv = 1.0f / lsum;
        float v0 = acc0 * inv + bias_gat[cb + 0];
        float v1 = acc1 * inv + bias_gat[cb + 1];
        float v2 = acc2 * inv + bias_gat[cb + 2];
        float v3 = acc3 * inv + bias_gat[cb + 3];

        float s = v0 + v1 + v2 + v3;
        #pragma unroll
        for (int m = 1; m < 64; m <<= 1) s += __shfl_xor(s, m);
        float mean = s * (1.0f / 256.0f);
        float d0 = v0 - mean, d1 = v1 - mean, d2 = v2 - mean, d3 = v3 - mean;
        float sq = d0 * d0 + d1 * d1 + d2 * d2 + d3 * d3;
        #pragma unroll
        for (int m = 1; m < 64; m <<= 1) sq += __shfl_xor(sq, m);
        float rstd = rsqrtf(sq * (1.0f / 256.0f) + 1e-5f);
        float4 o;
        o.x = d0 * rstd * g1[cb + 0] + be1[cb + 0];
        o.y = d1 * rstd * g1[cb + 1] + be1[cb + 1];
        o.z = d2 * rstd * g1[cb + 2] + be1[cb + 2];
        o.w = d3 * rstd * g1[cb + 3] + be1[cb + 3];
        store4(&out[(size_t)node * HIDDEN + cb], o);
    }
}

// ---------------- LN2(gout) + gated combine ----------------
__global__ __launch_bounds__(256) void combine_kernel(
    const bf16* __restrict__ gout, const bf16* __restrict__ localout,
    const float* __restrict__ alpha_p,
    const float* __restrict__ g2, const float* __restrict__ be2,
    bf16* __restrict__ combined)
{
    int wave = threadIdx.x >> 6;
    int lane = threadIdx.x & 63;
    int node = blockIdx.x * 4 + wave;
    int cb = lane * 4;
    float4 gv = load4(&gout[(size_t)node * HIDDEN + cb]);
    float s = gv.x + gv.y + gv.z + gv.w;
    #pragma unroll
    for (int m = 1; m < 64; m <<= 1) s += __shfl_xor(s, m);
    float mean = s * (1.0f / 256.0f);
    float d0 = gv.x - mean, d1 = gv.y - mean, d2 = gv.z - mean, d3 = gv.w - mean;
    float sq = d0 * d0 + d1 * d1 + d2 * d2 + d3 * d3;
    #pragma unroll
    for (int m = 1; m < 64; m <<= 1) sq += __shfl_xor(sq, m);
    float rstd = rsqrtf(sq * (1.0f / 256.0f) + 1e-5f);
    float n0 = d0 * rstd * g2[cb + 0] + be2[cb + 0];
    float n1 = d1 * rstd * g2[cb + 1] + be2[cb + 1];
    float n2 = d2 * rstd * g2[cb + 2] + be2[cb + 2];
    float n3 = d3 * rstd * g2[cb + 3] + be2[cb + 3];
    float a = 1.0f / (1.0f + __expf(-alpha_p[0]));
    float4 lv = load4(&localout[(size_t)node * HIDDEN + cb]);
    float4 o;
    o.x = a * lv.x + (1.0f - a) * n0;
    o.y = a * lv.y + (1.0f - a) * n1;
    o.z = a * lv.z + (1.0f - a) * n2;
    o.w = a * lv.w + (1.0f - a) * n3;
    store4(&combined[(size_t)node * HIDDEN + cb], o);
}

// ---------------- final LN3 in-place on fp32 out ----------------
__global__ __launch_bounds__(256) void finalln_kernel(
    float* __restrict__ out,
    const float* __restrict__ g3, const float* __restrict__ be3)
{
    int wave = threadIdx.x >> 6;
    int lane = threadIdx.x & 63;
    int node = blockIdx.x * 4 + wave;
    int cb = lane * 4;
    float4 v = *(const float4*)&out[(size_t)node * HIDDEN + cb];
    float s = v.x + v.y + v.z + v.w;
    #pragma unroll
    for (int m = 1; m < 64; m <<= 1) s += __shfl_xor(s, m);
    float mean = s * (1.0f / 256.0f);
    float d0 = v.x - mean, d1 = v.y - mean, d2 = v.z - mean, d3 = v.w - mean;
    float sq = d0 * d0 + d1 * d1 + d2 * d2 + d3 * d3;
    #pragma unroll
    for (int m = 1; m < 64; m <<= 1) sq += __shfl_xor(sq, m);
    float rstd = rsqrtf(sq * (1.0f / 256.0f) + 1e-5f);
    float4 o;
    o.x = d0 * rstd * g3[cb + 0] + be3[cb + 0];
    o.y = d1 * rstd * g3[cb + 1] + be3[cb + 1];
    o.z = d2 * rstd * g3[cb + 2] + be3[cb + 2];
    o.w = d3 * rstd * g3[cb + 3] + be3[cb + 3];
    *(float4*)&out[(size_t)node * HIDDEN + cb] = o;
}

// ---------------- launch ----------------
extern "C" void kernel_launch(void* const* d_in, const int* in_sizes, int n_in,
                              void* d_out, int out_size, void* d_ws, size_t ws_size,
                              hipStream_t stream) {
    const float* x          = (const float*)d_in[0];
    const float* edge_attr  = (const float*)d_in[1];
    const float* W_l        = (const float*)d_in[2];
    const float* b_l        = (const float*)d_in[3];
    const float* W_r        = (const float*)d_in[4];
    const float* b_r        = (const float*)d_in[5];
    const float* W_e        = (const float*)d_in[6];
    const float* att        = (const float*)d_in[7];
    const float* bias_gat   = (const float*)d_in[8];
    const float* in_proj_w  = (const float*)d_in[9];
    const float* in_proj_b  = (const float*)d_in[10];
    const float* out_proj_w = (const float*)d_in[11];
    const float* out_proj_b = (const float*)d_in[12];
    const float* alpha_p    = (const float*)d_in[13];
    const float* W1         = (const float*)d_in[14];
    const float* b1         = (const float*)d_in[15];
    const float* W2         = (const float*)d_in[16];
    const float* b2         = (const float*)d_in[17];
    const float* g1  = (const float*)d_in[18];
    const float* be1 = (const float*)d_in[19];
    const float* g2  = (const float*)d_in[20];
    const float* be2 = (const float*)d_in[21];
    const float* g3  = (const float*)d_in[22];
    const float* be3 = (const float*)d_in[23];
    const int* edge_index = (const int*)d_in[24];

    char* base = (char*)d_ws;
    const size_t MB = 1024 * 1024;
    const size_t KB = 1024;
    // graph prep [0, 3 MiB)
    float* deg     = (float*)(base + 0);
    float* ea_sum  = (float*)(base + 131072);
    int*   fill    = (int*)  (base + 393216);
    int*   row_ptr = (int*)  (base + 524288);
    // bf16 weights [3 MiB, ~5 MiB)
    bf16* wlrb = (bf16*)(base + 3 * MB);              // 512x256
    bf16* wipb = (bf16*)(base + 3 * MB + 256 * KB);   // 768x256
    bf16* wopb = (bf16*)(base + 3 * MB + 640 * KB);   // 256x256
    bf16* w1b  = (bf16*)(base + 3 * MB + 768 * KB);   // 1024x256
    bf16* w2b  = (bf16*)(base + 3 * MB + 1280 * KB);  // 256x1024
    float* blr  = (float*)(base + 5 * MB);            // 512 floats
    float* ipb2 = (float*)(base + 5 * MB + 4 * KB);   // 768 floats
    // big bf16 buffers (aliased; peak ~96.6 MiB)
    bf16* xb       = (bf16*)(base + 8 * MB);    // [8,24)
    bf16* qkv      = (bf16*)(base + 24 * MB);   // [24,72)
    bf16* attnout  = (bf16*)(base + 72 * MB);   // [72,88)
    bf16* gout     = (bf16*)(base + 24 * MB);   // [24,40)  (qkv dead)
    bf16* xl       = (bf16*)(base + 40 * MB);   // [40,56)
    bf16* xr       = (bf16*)(base + 56 * MB);   // [56,72)
    bf16* localout = (bf16*)(base + 72 * MB);   // [72,88)  (attnout dead)
    bf16* combined = (bf16*)(base + 8 * MB);    // [8,24)   (xb dead)
    bf16* h1       = (bf16*)(base + 24 * MB);   // [24,88)  full (gout/xl/xr/localout dead)
    int4* erec     = (int4*)(base + 88 * MB);   // [88, 96.6)
    float* out = (float*)d_out;

    // ---- GAT graph prep ----
    zero_kernel<<<(2 * N_NODES + 255) / 256, 256, 0, stream>>>(deg, ea_sum, fill);
    deg_kernel<<<E_EDGES / 256, 256, 0, stream>>>(edge_index, edge_attr, deg, ea_sum);
    scan_kernel<<<1, 1024, 0, stream>>>(deg, row_ptr);
    fill_kernel<<<(E_EDGES + N_NODES + 255) / 256, 256, 0, stream>>>(
        edge_index, edge_attr, ea_sum, deg, row_ptr, fill, erec);

    // ---- conversions (single launch) ----
    convall<<<11009, 256, 0, stream>>>(x, W_l, W_r, W1, W2, in_proj_w, out_proj_w,
                                       b_l, b_r, in_proj_b,
                                       xb, wlrb, w1b, w2b, wipb, wopb, blr, ipb2);

    // ---- MHA path first ----
    mfma_gemm<0><<<dim3(6, 256), 256, 0, stream>>>(
        xb, wipb, ipb2, (const bf16*)nullptr, qkv, N_NODES, 768, 256);
    attn_mfma<<<NGRAPH * NHEAD * 2, 256, 0, stream>>>(qkv, attnout);
    mfma_gemm<0><<<dim3(2, 256), 256, 0, stream>>>(
        attnout, wopb, out_proj_b, (const bf16*)nullptr, gout, N_NODES, 256, 256);

    // ---- GAT path (fused xl|xr GEMM, dual split output) ----
    mfma_gemm<3><<<dim3(4, 256), 256, 0, stream>>>(
        xb, wlrb, blr, (const bf16*)xr, xl, N_NODES, 512, 256);
    gat_kernel<<<N_NODES / 2, 256, 0, stream>>>(
        xl, xr, row_ptr, erec, W_e, att, bias_gat, g1, be1, localout);

    // ---- LN2 + gated combine ----
    combine_kernel<<<N_NODES / 4, 256, 0, stream>>>(
        gout, localout, alpha_p, g2, be2, combined);

    // ---- FFN full-size; ffn2 writes fp32 pre-LN (bias+residual) to d_out ----
    mfma_gemm<1><<<dim3(8, 256), 256, 0, stream>>>(
        combined, w1b, b1, (const bf16*)nullptr, h1, N_NODES, 1024, 256);
    mfma_gemm<4><<<dim3(2, 256), 256, 0, stream>>>(
        h1, w2b, b2, combined, (bf16*)out, N_NODES, 256, 1024);

    // ---- LN3 in place ----
    finalln_kernel<<<N_NODES / 4, 256, 0, stream>>>(out, g3, be3);
}

// Round 10
// 579.392 us; speedup vs baseline: 1.1808x; 1.0157x over previous
//
#include <hip/hip_runtime.h>
#include <math.h>

#define N_NODES 32768
#define E_EDGES 524288
#define HIDDEN  256
#define NPG     512
#define NGRAPH  64
#define NHEAD   8
#define CDIM    32

typedef unsigned short bf16;
typedef __attribute__((ext_vector_type(8))) short short8;
typedef __attribute__((ext_vector_type(4))) float f4;

#define AS1 __attribute__((address_space(1)))
#define AS3 __attribute__((address_space(3)))

__device__ __forceinline__ void cp16(const bf16* g, bf16* l) {
    __builtin_amdgcn_global_load_lds((AS1 const unsigned int*)(const void*)g,
                                     (AS3 unsigned int*)(void*)l, 16, 0, 0);
}

// ---------------- bf16 helpers ----------------
__device__ inline float bf2f(unsigned short u) {
    union { unsigned int i; float f; } v; v.i = ((unsigned int)u) << 16; return v.f;
}
__device__ inline unsigned short f2bf(float f) {
    union { float f; unsigned int i; } v; v.f = f;
    unsigned int x = v.i;
    return (unsigned short)((x + 0x7FFFu + ((x >> 16) & 1u)) >> 16);
}
__device__ inline unsigned short f2bf_trunc(float f) {
    return (unsigned short)(__float_as_uint(f) >> 16);
}
__device__ inline float4 load4(const float* p) { return *(const float4*)p; }
__device__ inline float4 load4(const bf16* p) {
    ushort4 u = *(const ushort4*)p;
    return make_float4(bf2f(u.x), bf2f(u.y), bf2f(u.z), bf2f(u.w));
}
__device__ inline void store4(float* p, float4 v) { *(float4*)p = v; }
__device__ inline void store4(bf16* p, float4 v) {
    ushort4 u; u.x = f2bf(v.x); u.y = f2bf(v.y); u.z = f2bf(v.z); u.w = f2bf(v.w);
    *(ushort4*)p = u;
}

// ---------------- small utility kernels ----------------

__global__ void zero_kernel(float* deg, float* ea_sum, int* fill) {
    int i = blockIdx.x * blockDim.x + threadIdx.x;
    if (i < 2 * N_NODES) ea_sum[i] = 0.0f;
    if (i < N_NODES) { deg[i] = 0.0f; fill[i] = 0; }
}

__global__ void deg_kernel(const int* __restrict__ ei, const float* __restrict__ edge_attr,
                           float* deg, float* ea_sum) {
    int e = blockIdx.x * blockDim.x + threadIdx.x;
    if (e >= E_EDGES) return;
    int d = ei[E_EDGES + e];
    atomicAdd(&deg[d], 1.0f);
    atomicAdd(&ea_sum[2 * d + 0], edge_attr[2 * e + 0]);
    atomicAdd(&ea_sum[2 * d + 1], edge_attr[2 * e + 1]);
}

__global__ __launch_bounds__(1024) void scan_kernel(const float* __restrict__ deg, int* row_ptr) {
    __shared__ int part[1024];
    int t = threadIdx.x;
    int base = t * 32;
    int loc[32];
    int s = 0;
    #pragma unroll
    for (int j = 0; j < 32; j++) {
        loc[j] = s;
        s += (int)deg[base + j] + 1;
    }
    int mysum = s;
    part[t] = s;
    __syncthreads();
    for (int off = 1; off < 1024; off <<= 1) {
        int v = 0;
        if (t >= off) v = part[t - off];
        __syncthreads();
        part[t] += v;
        __syncthreads();
    }
    int offset = part[t] - mysum;
    #pragma unroll
    for (int j = 0; j < 32; j++) row_ptr[base + j] = offset + loc[j];
    if (t == 1023) row_ptr[N_NODES] = part[1023];
}

// CSR fill with PACKED 16B edge records: {src, ea0, ea1, 0}; self-loop mean inline
__global__ void fill_kernel(const int* __restrict__ ei, const float* __restrict__ edge_attr,
                            const float* __restrict__ ea_sum, const float* __restrict__ deg,
                            const int* __restrict__ row_ptr, int* fill, int4* __restrict__ erec) {
    int tid = blockIdx.x * blockDim.x + threadIdx.x;
    if (tid >= E_EDGES + N_NODES) return;
    int d, src; float a0, a1;
    if (tid < E_EDGES) {
        d = ei[E_EDGES + tid];
        src = ei[tid];
        a0 = edge_attr[2 * tid + 0];
        a1 = edge_attr[2 * tid + 1];
    } else {
        d = tid - E_EDGES;
        src = d;
        float dm = fmaxf(deg[d], 1.0f);
        a0 = ea_sum[2 * d + 0] / dm;
        a1 = ea_sum[2 * d + 1] / dm;
    }
    int pos = row_ptr[d] + atomicAdd(&fill[d], 1);
    int4 r;
    r.x = src;
    r.y = __float_as_int(a0);
    r.z = __float_as_int(a1);
    r.w = 0;
    erec[pos] = r;
}

// ---------------- all conversions in one launch ----------------
// wcat rows: 0..767 in_proj (q rows prescaled by SCALE*log2e), 768..1023 W_l^T, 1024..1279 W_r^T
#define QSCALE 0.25506882685716462f
__global__ void convall(const float* __restrict__ x,
                        const float* __restrict__ W_l, const float* __restrict__ W_r,
                        const float* __restrict__ W1, const float* __restrict__ W2,
                        const float* __restrict__ in_proj_w, const float* __restrict__ out_proj_w,
                        const float* __restrict__ b_l, const float* __restrict__ b_r,
                        const float* __restrict__ in_proj_b,
                        bf16* xb, bf16* wcat, bf16* w1b, bf16* w2b,
                        bf16* wopb, float* bcat)
{
    int b = blockIdx.x, t = threadIdx.x;
    if (b < 8192) {                      // x copy (float4)
        int i = b * 256 + t;
        store4(&xb[i * 4], *(const float4*)&x[i * 4]);
    } else if (b < 8960) {               // in_proj_w [768][256] copy; q rows scaled
        int i = (b - 8192) * 256 + t;
        float v = in_proj_w[i];
        if (i < 65536) v *= QSCALE;
        wcat[i] = f2bf(v);
    } else if (b < 9216) {               // W_l^T -> wcat rows 768..1023
        int i = (b - 8960) * 256 + t; int k = i >> 8, n = i & 255;
        wcat[(768 + n) * 256 + k] = f2bf(W_l[i]);
    } else if (b < 9472) {               // W_r^T -> wcat rows 1024..1279
        int i = (b - 9216) * 256 + t; int k = i >> 8, n = i & 255;
        wcat[(1024 + n) * 256 + k] = f2bf(W_r[i]);
    } else if (b < 10496) {              // W1 [256][1024] -> w1b[n*256+k]
        int i = (b - 9472) * 256 + t; int k = i >> 10, n = i & 1023;
        w1b[n * 256 + k] = f2bf(W1[i]);
    } else if (b < 11520) {              // W2 [1024][256] -> w2b[n*1024+k]
        int i = (b - 10496) * 256 + t; int k = i >> 8, n = i & 255;
        w2b[n * 1024 + k] = f2bf(W2[i]);
    } else if (b < 11584) {              // out_proj_w straight
        int i = (b - 11520) * 256 + t;
        store4(&wopb[i * 4], *(const float4*)&out_proj_w[i * 4]);
    } else {                             // bcat: scaled in_proj_b | b_l | b_r
        #pragma unroll
        for (int j = 0; j < 5; j++) {
            int idx = j * 256 + t;
            float v;
            if (idx < 768) { v = in_proj_b[idx]; if (idx < 256) v *= QSCALE; }
            else if (idx < 1024) v = b_l[idx - 768];
            else v = b_r[idx - 1024];
            bcat[idx] = v;
        }
    }
}

// ---------------- MFMA bf16 GEMM (m97-style staging) ----------------
// EPI: 0 bias, 1 bias+gelu, 4 bias+residual(res bf16)->fp32 (float*)C,
//      5 merged 5-slab routing: slabs 0-2 -> qkv[gm*768+gn], 3 -> res(xl), 4 -> d2(xr)
template <int EPI>
__global__ __launch_bounds__(256) void mfma_gemm(
    const bf16* __restrict__ A, const bf16* __restrict__ Wb,
    const float* __restrict__ bias, const bf16* __restrict__ res,
    bf16* __restrict__ C, int M, int N, int K, bf16* __restrict__ d2)
{
    __shared__ bf16 lds[2 * 128 * 64];
    bf16* As = lds;
    bf16* Bs = lds + 128 * 64;
    int tid = threadIdx.x;
    int wave = tid >> 6, lane = tid & 63;
    int quad = lane >> 4, l16 = lane & 15;
    int n0 = blockIdx.x * 128, m0 = blockIdx.y * 128;
    int wm = (wave & 1) * 64, wn = (wave >> 1) * 64;

    f4 acc[4][4] = {};
    int srow = tid >> 3;
    int scol = (tid & 7) * 8;

    for (int k0 = 0; k0 < K; k0 += 64) {
        #pragma unroll
        for (int i = 0; i < 4; i++) {
            int row = i * 32 + srow;
            cp16(&A[(size_t)(m0 + row) * K + k0 + scol], &As[row * 64 + scol]);
            cp16(&Wb[(size_t)(n0 + row) * K + k0 + scol], &Bs[row * 64 + scol]);
        }
        __syncthreads();
        #pragma unroll
        for (int ks = 0; ks < 2; ks++) {
            short8 af[4], bfr[4];
            #pragma unroll
            for (int mt = 0; mt < 4; mt++)
                af[mt] = *(const short8*)&As[(wm + mt * 16 + l16) * 64 + ks * 32 + quad * 8];
            #pragma unroll
            for (int nt = 0; nt < 4; nt++)
                bfr[nt] = *(const short8*)&Bs[(wn + nt * 16 + l16) * 64 + ks * 32 + quad * 8];
            #pragma unroll
            for (int mt = 0; mt < 4; mt++)
                #pragma unroll
                for (int nt = 0; nt < 4; nt++)
                    acc[mt][nt] = __builtin_amdgcn_mfma_f32_16x16x32_bf16(
                        af[mt], bfr[nt], acc[mt][nt], 0, 0, 0);
        }
        __syncthreads();
    }

    float* epi = (float*)lds + wave * 16 * 68;
    int row = lane >> 2;
    int cb = (lane & 3) * 16;
    int gn = n0 + wn + cb;
    float bb[16];
    *(float4*)&bb[0]  = *(const float4*)&bias[gn + 0];
    *(float4*)&bb[4]  = *(const float4*)&bias[gn + 4];
    *(float4*)&bb[8]  = *(const float4*)&bias[gn + 8];
    *(float4*)&bb[12] = *(const float4*)&bias[gn + 12];

    for (int mt = 0; mt < 4; mt++) {
        #pragma unroll
        for (int nt = 0; nt < 4; nt++)
            #pragma unroll
            for (int r = 0; r < 4; r++)
                epi[(quad * 4 + r) * 68 + nt * 16 + l16] = acc[mt][nt][r];
        float vv[16];
        *(float4*)&vv[0]  = *(float4*)&epi[row * 68 + cb + 0];
        *(float4*)&vv[4]  = *(float4*)&epi[row * 68 + cb + 4];
        *(float4*)&vv[8]  = *(float4*)&epi[row * 68 + cb + 8];
        *(float4*)&vv[12] = *(float4*)&epi[row * 68 + cb + 12];
        int gm = m0 + wm + mt * 16 + row;
        #pragma unroll
        for (int j = 0; j < 16; j++) vv[j] += bb[j];
        if (EPI == 1) {
            #pragma unroll
            for (int j = 0; j < 16; j++)
                vv[j] = 0.5f * vv[j] * (1.0f + erff(vv[j] * 0.70710678118654752f));
        } else if (EPI == 4) {
            ushort rr[16];
            const bf16* rp = &res[(size_t)gm * N + gn];
            *(int4*)&rr[0] = *(const int4*)&rp[0];
            *(int4*)&rr[8] = *(const int4*)&rp[8];
            #pragma unroll
            for (int j = 0; j < 16; j++) vv[j] += bf2f(rr[j]);
            float* cf = (float*)C + (size_t)gm * N + gn;
            *(float4*)&cf[0]  = *(float4*)&vv[0];
            *(float4*)&cf[4]  = *(float4*)&vv[4];
            *(float4*)&cf[8]  = *(float4*)&vv[8];
            *(float4*)&cf[12] = *(float4*)&vv[12];
            continue;
        }
        ushort o16[16];
        #pragma unroll
        for (int j = 0; j < 16; j++) o16[j] = f2bf(vv[j]);
        bf16* cp;
        if (EPI == 5) {
            if (gn < 768) {
                cp = &C[(size_t)gm * 768 + gn];           // interleaved qkv
            } else if (gn < 1024) {
                cp = &((bf16*)res)[(size_t)gm * 256 + (gn - 768)];   // xl
            } else {
                cp = &d2[(size_t)gm * 256 + (gn - 1024)];            // xr
            }
        } else {
            cp = &C[(size_t)gm * N + gn];
        }
        *(int4*)&cp[0] = *(int4*)&o16[0];
        *(int4*)&cp[8] = *(int4*)&o16[8];
    }
}

// ---------------- MFMA flash attention (q prescaled; exp2; trunc pack) ----
__global__ __launch_bounds__(256) void attn_mfma(
    const bf16* __restrict__ qkv, bf16* __restrict__ attnout)
{
    __shared__ bf16 Ks[128 * 40];
    __shared__ bf16 Vt[32 * 136];
    __shared__ bf16 Pb[4 * 64 * 40];

    int b = blockIdx.x;
    int g = b >> 4, h = (b >> 1) & 7, hlf = b & 1;
    int tid = threadIdx.x;
    int wave = tid >> 6, lane = tid & 63;
    int quad = lane >> 4, l16 = lane & 15;
    int qbase = hlf * 256 + wave * 64;
    bf16* Pw = &Pb[wave * 64 * 40];

    short8 qf[4];
    #pragma unroll
    for (int mt = 0; mt < 4; mt++) {
        size_t node = (size_t)(g * NPG + qbase + mt * 16 + l16);
        qf[mt] = *(const short8*)&qkv[node * 768 + h * CDIM + quad * 8];
    }

    f4 oacc[4][2] = {};
    float lacc[4][4] = {};

    for (int c = 0; c < 4; c++) {
        int kk0 = c * 128;
        __syncthreads();
        #pragma unroll
        for (int i = 0; i < 2; i++) {
            int idx = i * 256 + tid;
            int key = idx >> 2, kc = (idx & 3) * 8;
            *(int4*)&Ks[key * 40 + kc] =
                *(const int4*)&qkv[(size_t)(g * NPG + kk0 + key) * 768 + 256 + h * CDIM + kc];
        }
        {
            int key = tid >> 1, dblk = (tid & 1) * 16;
            ushort tmp[16];
            const bf16* vp = &qkv[(size_t)(g * NPG + kk0 + key) * 768 + 512 + h * CDIM + dblk];
            *(int4*)&tmp[0] = *(const int4*)&vp[0];
            *(int4*)&tmp[8] = *(const int4*)&vp[8];
            #pragma unroll
            for (int j = 0; j < 16; j++) Vt[(dblk + j) * 136 + key] = tmp[j];
        }
        __syncthreads();

        for (int sub = 0; sub < 4; sub++) {
            int ks0 = sub * 32;
            short8 kf[2];
            #pragma unroll
            for (int nt = 0; nt < 2; nt++)
                kf[nt] = *(const short8*)&Ks[(ks0 + nt * 16 + l16) * 40 + quad * 8];
            #pragma unroll
            for (int mt = 0; mt < 4; mt++) {
                #pragma unroll
                for (int nt = 0; nt < 2; nt++) {
                    f4 z = {0.f, 0.f, 0.f, 0.f};
                    f4 s = __builtin_amdgcn_mfma_f32_16x16x32_bf16(qf[mt], kf[nt], z, 0, 0, 0);
                    #pragma unroll
                    for (int r = 0; r < 4; r++) {
                        float p = exp2f(s[r]);
                        lacc[mt][r] += p;
                        Pw[(mt * 16 + quad * 4 + r) * 40 + nt * 16 + l16] = f2bf_trunc(p);
                    }
                }
            }
            short8 vf[2];
            #pragma unroll
            for (int dt = 0; dt < 2; dt++)
                vf[dt] = *(const short8*)&Vt[(dt * 16 + l16) * 136 + ks0 + quad * 8];
            #pragma unroll
            for (int mt = 0; mt < 4; mt++) {
                short8 pf = *(const short8*)&Pw[(mt * 16 + l16) * 40 + quad * 8];
                #pragma unroll
                for (int dt = 0; dt < 2; dt++)
                    oacc[mt][dt] = __builtin_amdgcn_mfma_f32_16x16x32_bf16(
                        pf, vf[dt], oacc[mt][dt], 0, 0, 0);
            }
        }
    }

    #pragma unroll
    for (int mt = 0; mt < 4; mt++)
        #pragma unroll
        for (int r = 0; r < 4; r++) {
            float l = lacc[mt][r];
            l += __shfl_xor(l, 1);
            l += __shfl_xor(l, 2);
            l += __shfl_xor(l, 4);
            l += __shfl_xor(l, 8);
            lacc[mt][r] = l;
        }

    #pragma unroll
    for (int mt = 0; mt < 4; mt++) {
        #pragma unroll
        for (int dt = 0; dt < 2; dt++) {
            #pragma unroll
            for (int r = 0; r < 4; r++) {
                float v = oacc[mt][dt][r] / lacc[mt][r];
                size_t node = (size_t)(g * NPG + qbase + mt * 16 + quad * 4 + r);
                attnout[node * HIDDEN + h * CDIM + dt * 16 + l16] = f2bf(v);
            }
        }
    }
}

// ---------------- GATv2: 2 waves/node + depth-2 pipeline (r8-proven) ----
__device__ __forceinline__ void fetchrec(
    int i, int re, int node, const int4* __restrict__ erec,
    int& s, float& a0, float& a1)
{
    if (i < re) {
        int4 r = erec[i];
        s = r.x; a0 = __int_as_float(r.y); a1 = __int_as_float(r.z);
    } else {
        s = node; a0 = 0.f; a1 = 0.f;
    }
}

__global__ __launch_bounds__(256) void gat_kernel(
    const bf16* __restrict__ xl, const bf16* __restrict__ xr,
    const int* __restrict__ row_ptr, const int4* __restrict__ erec,
    const float* __restrict__ W_e, const float* __restrict__ att,
    const float* __restrict__ bias_gat,
    const float* __restrict__ g1, const float* __restrict__ be1,
    bf16* __restrict__ out)
{
    __shared__ float pacc[2][260];
    __shared__ float plsum[2][64];
    int wave = threadIdx.x >> 6;
    int lane = threadIdx.x & 63;
    int nloc = wave >> 1, half = wave & 1;
    int node = blockIdx.x * 2 + nloc;
    int cb = lane * 4;

    float4 xr4 = load4(&xr[(size_t)node * 256 + cb]);
    float4 we0 = *(const float4*)&W_e[cb];
    float4 we1 = *(const float4*)&W_e[HIDDEN + cb];
    float4 at4 = *(const float4*)&att[cb];

    int rs = row_ptr[node], re = row_ptr[node + 1];

    float lsum = 0.f;
    float acc0 = 0.f, acc1 = 0.f, acc2 = 0.f, acc3 = 0.f;

    int i0 = rs + half;
    int s0, s1; float a00, a01, a10, a11;
    fetchrec(i0,     re, node, erec, s0, a00, a01);
    fetchrec(i0 + 2, re, node, erec, s1, a10, a11);
    ushort4 xu0 = *(const ushort4*)&xl[(size_t)s0 * 256 + cb];

    for (int i = i0; i < re; i += 2) {
        int s2; float a20, a21;
        fetchrec(i + 4, re, node, erec, s2, a20, a21);
        ushort4 xu1 = *(const ushort4*)&xl[(size_t)s1 * 256 + cb];

        float4 xl4 = make_float4(bf2f(xu0.x), bf2f(xu0.y), bf2f(xu0.z), bf2f(xu0.w));
        float t, p = 0.f;
        t = xl4.x + xr4.x + a00 * we0.x + a01 * we1.x; t = (t > 0.f) ? t : 0.2f * t; p += t * at4.x;
        t = xl4.y + xr4.y + a00 * we0.y + a01 * we1.y; t = (t > 0.f) ? t : 0.2f * t; p += t * at4.y;
        t = xl4.z + xr4.z + a00 * we0.z + a01 * we1.z; t = (t > 0.f) ? t : 0.2f * t; p += t * at4.z;
        t = xl4.w + xr4.w + a00 * we0.w + a01 * we1.w; t = (t > 0.f) ? t : 0.2f * t; p += t * at4.w;
        p += __shfl_xor(p, 1);
        p += __shfl_xor(p, 2);
        p += __shfl_xor(p, 4);
        float w = __expf(p);
        lsum += w;
        acc0 += w * xl4.x; acc1 += w * xl4.y; acc2 += w * xl4.z; acc3 += w * xl4.w;

        s0 = s1; a00 = a10; a01 = a11; xu0 = xu1;
        s1 = s2; a10 = a20; a11 = a21;
    }

    if (half) {
        plsum[nloc][lane] = lsum;
        pacc[nloc][cb + 0] = acc0; pacc[nloc][cb + 1] = acc1;
        pacc[nloc][cb + 2] = acc2; pacc[nloc][cb + 3] = acc3;
    }
    __syncthreads();
    if (!half) {
        lsum += plsum[nloc][lane];
        acc0 += pacc[nloc][cb + 0]; acc1 += pacc[nloc][cb + 1];
        acc2 += pacc[nloc][cb + 2]; acc3 += pacc[nloc][cb + 3];

        float inv = 1.0f / lsum;
        float v0 = acc0 * inv + bias_gat[cb + 0];
        float v1 = acc1 * inv + bias_gat[cb + 1];
        float v2 = acc2 * inv + bias_gat[cb + 2];
        float v3 = acc3 * inv + bias_gat[cb + 3];

        float s = v0 + v1 + v2 + v3;
        #pragma unroll
        for (int m = 1; m < 64; m <<= 1) s += __shfl_xor(s, m);
        float mean = s * (1.0f / 256.0f);
        float d0 = v0 - mean, d1 = v1 - mean, d2 = v2 - mean, d3 = v3 - mean;
        float sq = d0 * d0 + d1 * d1 + d2 * d2 + d3 * d3;
        #pragma unroll
        for (int m = 1; m < 64; m <<= 1) sq += __shfl_xor(sq, m);
        float rstd = rsqrtf(sq * (1.0f / 256.0f) + 1e-5f);
        float4 o;
        o.x = d0 * rstd * g1[cb + 0] + be1[cb + 0];
        o.y = d1 * rstd * g1[cb + 1] + be1[cb + 1];
        o.z = d2 * rstd * g1[cb + 2] + be1[cb + 2];
        o.w = d3 * rstd * g1[cb + 3] + be1[cb + 3];
        store4(&out[(size_t)node * HIDDEN + cb], o);
    }
}

// ---------------- LN2(gout) + gated combine ----------------
__global__ __launch_bounds__(256) void combine_kernel(
    const bf16* __restrict__ gout, const bf16* __restrict__ localout,
    const float* __restrict__ alpha_p,
    const float* __restrict__ g2, const float* __restrict__ be2,
    bf16* __restrict__ combined)
{
    int wave = threadIdx.x >> 6;
    int lane = threadIdx.x & 63;
    int node = blockIdx.x * 4 + wave;
    int cb = lane * 4;
    float4 gv = load4(&gout[(size_t)node * HIDDEN + cb]);
    float s = gv.x + gv.y + gv.z + gv.w;
    #pragma unroll
    for (int m = 1; m < 64; m <<= 1) s += __shfl_xor(s, m);
    float mean = s * (1.0f / 256.0f);
    float d0 = gv.x - mean, d1 = gv.y - mean, d2 = gv.z - mean, d3 = gv.w - mean;
    float sq = d0 * d0 + d1 * d1 + d2 * d2 + d3 * d3;
    #pragma unroll
    for (int m = 1; m < 64; m <<= 1) sq += __shfl_xor(sq, m);
    float rstd = rsqrtf(sq * (1.0f / 256.0f) + 1e-5f);
    float n0 = d0 * rstd * g2[cb + 0] + be2[cb + 0];
    float n1 = d1 * rstd * g2[cb + 1] + be2[cb + 1];
    float n2 = d2 * rstd * g2[cb + 2] + be2[cb + 2];
    float n3 = d3 * rstd * g2[cb + 3] + be2[cb + 3];
    float a = 1.0f / (1.0f + __expf(-alpha_p[0]));
    float4 lv = load4(&localout[(size_t)node * HIDDEN + cb]);
    float4 o;
    o.x = a * lv.x + (1.0f - a) * n0;
    o.y = a * lv.y + (1.0f - a) * n1;
    o.z = a * lv.z + (1.0f - a) * n2;
    o.w = a * lv.w + (1.0f - a) * n3;
    store4(&combined[(size_t)node * HIDDEN + cb], o);
}

// ---------------- final LN3 in-place on fp32 out ----------------
__global__ __launch_bounds__(256) void finalln_kernel(
    float* __restrict__ out,
    const float* __restrict__ g3, const float* __restrict__ be3)
{
    int wave = threadIdx.x >> 6;
    int lane = threadIdx.x & 63;
    int node = blockIdx.x * 4 + wave;
    int cb = lane * 4;
    float4 v = *(const float4*)&out[(size_t)node * HIDDEN + cb];
    float s = v.x + v.y + v.z + v.w;
    #pragma unroll
    for (int m = 1; m < 64; m <<= 1) s += __shfl_xor(s, m);
    float mean = s * (1.0f / 256.0f);
    float d0 = v.x - mean, d1 = v.y - mean, d2 = v.z - mean, d3 = v.w - mean;
    float sq = d0 * d0 + d1 * d1 + d2 * d2 + d3 * d3;
    #pragma unroll
    for (int m = 1; m < 64; m <<= 1) sq += __shfl_xor(sq, m);
    float rstd = rsqrtf(sq * (1.0f / 256.0f) + 1e-5f);
    float4 o;
    o.x = d0 * rstd * g3[cb + 0] + be3[cb + 0];
    o.y = d1 * rstd * g3[cb + 1] + be3[cb + 1];
    o.z = d2 * rstd * g3[cb + 2] + be3[cb + 2];
    o.w = d3 * rstd * g3[cb + 3] + be3[cb + 3];
    *(float4*)&out[(size_t)node * HIDDEN + cb] = o;
}

// ---------------- launch ----------------
extern "C" void kernel_launch(void* const* d_in, const int* in_sizes, int n_in,
                              void* d_out, int out_size, void* d_ws, size_t ws_size,
                              hipStream_t stream) {
    const float* x          = (const float*)d_in[0];
    const float* edge_attr  = (const float*)d_in[1];
    const float* W_l        = (const float*)d_in[2];
    const float* b_l        = (const float*)d_in[3];
    const float* W_r        = (const float*)d_in[4];
    const float* b_r        = (const float*)d_in[5];
    const float* W_e        = (const float*)d_in[6];
    const float* att        = (const float*)d_in[7];
    const float* bias_gat   = (const float*)d_in[8];
    const float* in_proj_w  = (const float*)d_in[9];
    const float* in_proj_b  = (const float*)d_in[10];
    const float* out_proj_w = (const float*)d_in[11];
    const float* out_proj_b = (const float*)d_in[12];
    const float* alpha_p    = (const float*)d_in[13];
    const float* W1         = (const float*)d_in[14];
    const float* b1         = (const float*)d_in[15];
    const float* W2         = (const float*)d_in[16];
    const float* b2         = (const float*)d_in[17];
    const float* g1  = (const float*)d_in[18];
    const float* be1 = (const float*)d_in[19];
    const float* g2  = (const float*)d_in[20];
    const float* be2 = (const float*)d_in[21];
    const float* g3  = (const float*)d_in[22];
    const float* be3 = (const float*)d_in[23];
    const int* edge_index = (const int*)d_in[24];

    char* base = (char*)d_ws;
    const size_t MB = 1024 * 1024;
    const size_t KB = 1024;
    // graph prep [0, 3 MiB)
    float* deg     = (float*)(base + 0);
    float* ea_sum  = (float*)(base + 131072);
    int*   fill    = (int*)  (base + 393216);
    int*   row_ptr = (int*)  (base + 524288);
    // bf16 weights [3 MiB, ~5 MiB)
    bf16* wcat = (bf16*)(base + 3 * MB);              // 1280x256 (640 KB)
    bf16* w1b  = (bf16*)(base + 3 * MB + 704 * KB);   // 1024x256 (512 KB)
    bf16* w2b  = (bf16*)(base + 3 * MB + 1216 * KB);  // 256x1024 (512 KB)
    bf16* wopb = (bf16*)(base + 3 * MB + 1728 * KB);  // 256x256  (128 KB)
    float* bcat = (float*)(base + 5 * MB);            // 1280 floats
    // big bf16 buffers (aliased; peak ~96.6 MiB)
    bf16* xb       = (bf16*)(base + 8 * MB);    // [8,24)
    bf16* qkv      = (bf16*)(base + 24 * MB);   // [24,72)
    bf16* xl       = (bf16*)(base + 40 * MB);   // NOTE: xl/xr live AFTER qkv is dead? No:
    // careful — qkv [24,72) is alive during attn; xl/xr written by the same merged GEMM.
    // Place xl at [72,88) and xr at [88,104)? erec is at [88,...). Re-plan:
    //   qkv  [24,72)   alive: merged-GEMM .. attn
    //   xl   [72,88)   alive: merged-GEMM .. gat
    //   xr   [104,120) alive: merged-GEMM .. gat
    //   attnout [8,24)+? xb dead after merged GEMM -> attnout = [8,24)
    //   localout: [24,40) after attn? qkv dead after attn -> localout [24,40)
    //   BUT gat (producing localout) runs BEFORE attn in this schedule; keep gat after attn.
    bf16* attnout  = (bf16*)(base + 8 * MB);    // [8,24)   (xb dead after merged GEMM)
    bf16* gout     = (bf16*)(base + 24 * MB);   // [24,40)  (qkv dead after attn)
    bf16* localout = (bf16*)(base + 40 * MB);   // [40,56)  (qkv dead after attn)
    bf16* combined = (bf16*)(base + 56 * MB);   // [56,72)  (qkv dead after attn)
    bf16* h1       = (bf16*)(base + 120 * MB);  // [120,184) full 64 MB
    int4* erec     = (int4*)(base + 88 * MB);   // [88, 96.6)
    bf16* xl_      = (bf16*)(base + 72 * MB);   // [72,88)
    bf16* xr_      = (bf16*)(base + 104 * MB);  // [104,120)
    float* out = (float*)d_out;

    // ---- GAT graph prep ----
    zero_kernel<<<(2 * N_NODES + 255) / 256, 256, 0, stream>>>(deg, ea_sum, fill);
    deg_kernel<<<E_EDGES / 256, 256, 0, stream>>>(edge_index, edge_attr, deg, ea_sum);
    scan_kernel<<<1, 1024, 0, stream>>>(deg, row_ptr);
    fill_kernel<<<(E_EDGES + N_NODES + 255) / 256, 256, 0, stream>>>(
        edge_index, edge_attr, ea_sum, deg, row_ptr, fill, erec);

    // ---- conversions (single launch) ----
    convall<<<11585, 256, 0, stream>>>(x, W_l, W_r, W1, W2, in_proj_w, out_proj_w,
                                       b_l, b_r, in_proj_b,
                                       xb, wcat, w1b, w2b, wopb, bcat);

    // ---- merged qkv|xl|xr GEMM (one pass over xb) ----
    mfma_gemm<5><<<dim3(10, 256), 256, 0, stream>>>(
        xb, wcat, bcat, xl_, qkv, N_NODES, 1280, 256, xr_);

    // ---- attention, then gat (qkv frees buffers for downstream) ----
    attn_mfma<<<NGRAPH * NHEAD * 2, 256, 0, stream>>>(qkv, attnout);
    gat_kernel<<<N_NODES / 2, 256, 0, stream>>>(
        xl_, xr_, row_ptr, erec, W_e, att, bias_gat, g1, be1, localout);

    // ---- out_proj ----
    mfma_gemm<0><<<dim3(2, 256), 256, 0, stream>>>(
        attnout, wopb, out_proj_b, (const bf16*)nullptr, gout, N_NODES, 256, 256, (bf16*)nullptr);

    // ---- LN2 + gated combine ----
    combine_kernel<<<N_NODES / 4, 256, 0, stream>>>(
        gout, localout, alpha_p, g2, be2, combined);

    // ---- FFN; ffn2 writes fp32 pre-LN (bias+residual) to d_out ----
    mfma_gemm<1><<<dim3(8, 256), 256, 0, stream>>>(
        combined, w1b, b1, (const bf16*)nullptr, h1, N_NODES, 1024, 256, (bf16*)nullptr);
    mfma_gemm<4><<<dim3(2, 256), 256, 0, stream>>>(
        h1, w2b, b2, combined, (bf16*)out, N_NODES, 256, 1024, (bf16*)nullptr);

    // ---- LN3 in place ----
    finalln_kernel<<<N_NODES / 4, 256, 0, stream>>>(out, g3, be3);
}